// Round 6
// baseline (526.160 us; speedup 1.0000x reference)
//
#include <hip/hip_runtime.h>
#include <hip/hip_bf16.h>
#include <math.h>

#define Bx   256
#define Nx   512
#define SIGx 256
#define HIDx 256
#define OUTx 10
#define Hx   256

#define LDAP 72   // LDS k-stride for kGstd tiles (unchanged)

typedef __attribute__((ext_vector_type(8))) short bf16x8;
typedef __attribute__((ext_vector_type(4))) float f32x4;

__device__ inline ushort f2bf(float v) {
    __hip_bfloat16 h = __float2bfloat16(v);
    return *reinterpret_cast<ushort*>(&h);
}
__device__ inline float loadT(const __hip_bfloat16* p) { return __bfloat162float(*p); }

// ---------------------------------------------------------------------------
// Kernel A: sampling stage (mixture fields constant over m => unif dead).
// ---------------------------------------------------------------------------
__global__ __launch_bounds__(512) void kA_sample(
    const float* __restrict__ x, const float* __restrict__ z,
    const float* __restrict__ mg, float* __restrict__ feat,
    float* __restrict__ flp)
{
    int b = blockIdx.x;
    int n = threadIdx.x;
    int g = n >> 5;
    float mux = mg[g*6+1];
    float muy = mg[g*6+2];
    float sxv = expf(mg[g*6+3]);
    float syv = expf(mg[g*6+4]);
    float rho = tanhf(mg[g*6+5]);
    float z1 = z[((size_t)b*Nx + n)*2 + 0];
    float z2 = z[((size_t)b*Nx + n)*2 + 1];
    float omr2 = 1.0f - rho*rho;
    float xs = mux + sxv*z1;
    float ys = muy + syv*(rho*z1 + sqrtf(omr2)*z2);
    float dx = xs - mux, dy = ys - muy;
    float quad = (dx*dx/(sxv*sxv) - 2.0f*rho*dx*dy/(sxv*syv) + dy*dy/(syv*syv)) / omr2;
    float logprob = -1.8378770664093453f - logf(sxv*syv) - 0.5f*logf(omr2) - 0.5f*quad;
    float lx = tanhf(xs), ly = tanhf(ys);
    int px = (int)truncf(0.5f*(lx+1.0f)*(float)Hx - 0.1f);
    int py = (int)truncf(0.5f*(ly+1.0f)*(float)Hx - 0.1f);
    px = px < 0 ? 0 : (px > Hx-1 ? Hx-1 : px);
    py = py < 0 ? 0 : (py > Hx-1 ? Hx-1 : py);
    float pv = x[(size_t)b*Hx*Hx + (size_t)px*Hx + py];
    size_t fo = ((size_t)b*Nx + n)*3;
    feat[fo+0] = pv; feat[fo+1] = lx; feat[fo+2] = ly;

    __shared__ float red[512];
    red[n] = logprob;
    __syncthreads();
    for (int st = 256; st > 0; st >>= 1) {
        if (n < st) red[n] += red[n+st];
        __syncthreads();
    }
    if (n == 0) flp[b] = red[0];
}

// ---------------------------------------------------------------------------
// Prep: c1,c2 -> bf16; w2 -> w2t bf16 (transposed).
// ---------------------------------------------------------------------------
__global__ __launch_bounds__(256) void kPrep(
    const float* __restrict__ c1, const float* __restrict__ c2,
    const float* __restrict__ w2,
    ushort* __restrict__ c1h, ushort* __restrict__ c2h, ushort* __restrict__ w2t)
{
    int idx = blockIdx.x*256 + threadIdx.x;
    if (idx < SIGx*Nx) {
        c1h[idx] = f2bf(c1[idx]);
        c2h[idx] = f2bf(c2[idx]);
    }
    if (idx < HIDx*HIDx) {
        int i = idx >> 8, j = idx & 255;
        w2t[idx] = f2bf(w2[j*HIDx + i]);
    }
}

// ===========================================================================
// kGadjF / kGadj2: C[h][n] = sum_m A[h][m]*adj[m][n], bias+relu epilogue.
// Block = 256 h-rows x 128 n-cols (grid: 4 ct x BC). 4 waves, each 256x32.
// adj fragments generated IN REGISTERS (adj[m][n] = rcp(H[m]+c_n - xn*x_m
// - yn*y_m)). A tile in LDS, rotation-swizzled (phys kblk = (kb+r)&7,
// stride 64 shorts, no pad) -> conflict-free writes AND frag reads.
// FUSED=true: A generated from feat (h1 = feat@gc1_w, rank-3). FUSED=false:
// A loaded from global (h2t).
// ===========================================================================
template<bool FUSED>
__global__ __launch_bounds__(256) void kGadjT(
    const ushort* __restrict__ Aall, const float* __restrict__ featL,
    const float* __restrict__ w1, const float* __restrict__ bias,
    ushort* __restrict__ outAll)
{
    int b  = blockIdx.y;
    int ct = blockIdx.x;                       // 0..3
    const float* fb = featL + (size_t)b*Nx*3;
    ushort* outT = outAll + (size_t)b*HIDx*Nx;
    const ushort* A = Aall + (size_t)b*HIDx*Nx;

    __shared__ short Als[256*64];              // 32 KB, swizzled
    __shared__ float fpv[Nx], flx[Nx], fly[Nx], fH[Nx];
    __shared__ float w1s[3*HIDx];

    int t = threadIdx.x;
    for (int n = t; n < Nx; n += 256) {
        float lx = fb[n*3+1], ly = fb[n*3+2];
        if (FUSED) fpv[n] = fb[n*3+0];
        flx[n] = lx; fly[n] = ly;
        fH[n] = fmaf(0.5f*lx, lx, fmaf(0.5f*ly, ly, 1.0f));
    }
    if (FUSED) {
        for (int i = t; i < 3*HIDx; i += 256) w1s[i] = w1[i];
    }
    __syncthreads();

    int lane = t & 63, wave = t >> 6;
    int q = lane >> 4, c16 = lane & 15;
    int n0 = ct*128;

    // per-thread column constants (j = 0,1)
    float xn[2], yn[2], cn[2];
    #pragma unroll
    for (int j = 0; j < 2; ++j) {
        int n = n0 + wave*32 + j*16 + c16;
        xn[j] = flx[n]; yn[j] = fly[n];
        cn[j] = fmaf(0.5f*xn[j], xn[j], 0.5f*yn[j]*yn[j]);
    }

    f32x4 acc[16][2] = {};

    for (int kk = 0; kk < Nx; kk += 64) {
        // ---- stage/generate A tile: 256 rows x 64 k ----
        if (FUSED) {
            #pragma unroll
            for (int it = 0; it < 8; ++it) {
                int item = t + it*256;
                int r  = item & 255;
                int kb = item >> 8;
                int m0 = kk + kb*8;
                float w0 = w1s[r], wA = w1s[256+r], wB = w1s[512+r];
                union { ushort u[8]; float4 v; } pk;
                #pragma unroll
                for (int e = 0; e < 8; ++e) {
                    float v = fmaf(fpv[m0+e], w0, fmaf(flx[m0+e], wA, fly[m0+e]*wB));
                    pk.u[e] = f2bf(v);
                }
                int pkb = (kb + r) & 7;
                *(float4*)&Als[r*64 + pkb*8] = pk.v;
            }
        } else {
            #pragma unroll
            for (int cc = 0; cc < 8; ++cc) {
                int c  = t + cc*256;
                int r  = c >> 3;
                int kb = c & 7;
                float4 v = *(const float4*)(A + (size_t)r*Nx + kk + kb*8);
                int pkb = (kb + r) & 7;
                *(float4*)&Als[r*64 + pkb*8] = v;
            }
        }
        __syncthreads();

        #pragma unroll
        for (int ks = 0; ks < 64; ks += 32) {
            // ---- generate B fragments in registers ----
            bf16x8 bfr[2];
            int m0 = kk + ks + q*8;
            #pragma unroll
            for (int j = 0; j < 2; ++j) {
                union { ushort u[8]; bf16x8 v; } pb;
                #pragma unroll
                for (int e = 0; e < 8; ++e) {
                    float s = fmaf(-yn[j], fly[m0+e],
                              fmaf(-xn[j], flx[m0+e], fH[m0+e] + cn[j]));
                    pb.u[e] = f2bf(__builtin_amdgcn_rcpf(s));
                }
                bfr[j] = pb.v;
            }
            // ---- MFMA over all 16 row-fragments ----
            int pkb = (q + (ks >> 3) + c16) & 7;     // swizzle: i-invariant
            const short* abase = &Als[c16*64 + pkb*8];
            #pragma unroll
            for (int i = 0; i < 16; ++i) {
                bf16x8 af = *(const bf16x8*)(abase + i*16*64);
                acc[i][0] = __builtin_amdgcn_mfma_f32_16x16x32_bf16(af, bfr[0], acc[i][0], 0,0,0);
                acc[i][1] = __builtin_amdgcn_mfma_f32_16x16x32_bf16(af, bfr[1], acc[i][1], 0,0,0);
            }
        }
        __syncthreads();
    }

    // ---- epilogue: bias + relu -> bf16 ----
    #pragma unroll
    for (int i = 0; i < 16; ++i) {
        int rowb = i*16 + q*4;
        float4 bv = *(const float4*)&bias[rowb];
        #pragma unroll
        for (int j = 0; j < 2; ++j) {
            int col = n0 + wave*32 + j*16 + c16;
            float bb[4] = {bv.x, bv.y, bv.z, bv.w};
            #pragma unroll
            for (int r = 0; r < 4; ++r) {
                float v = fmaxf(acc[i][j][r] + bb[r], 0.0f);
                outT[(size_t)(rowb + r)*Nx + col] = f2bf(v);
            }
        }
    }
}

// ---------------------------------------------------------------------------
// kGstd: C[row][col] = sum_k Ash[row][k] * B[k][col]   (unchanged)
// ---------------------------------------------------------------------------
template<int K, int NC, bool TRB>
__global__ __launch_bounds__(256) void kGstd(
    const ushort* __restrict__ Ash, const ushort* __restrict__ Ball,
    ushort* __restrict__ outAll)
{
    constexpr int CT = NC / 128;
    int b  = blockIdx.y;
    int rt = blockIdx.x / CT;
    int ct = blockIdx.x % CT;
    const ushort* B = Ball + (size_t)b*HIDx*Nx;
    ushort* outp = outAll + (size_t)b*HIDx*NC;

    __shared__ short Als[128][LDAP];
    __shared__ short Bls[128][LDAP];
    int t = threadIdx.x;
    int lane = t & 63, wave = t >> 6;
    int wr = wave >> 1, wc = wave & 1;
    int q = lane >> 4, c16 = lane & 15;
    int r0 = rt*128, n0 = ct*128;
    f32x4 acc[4][4] = {};

    for (int kk = 0; kk < K; kk += 64) {
        #pragma unroll
        for (int cc = 0; cc < 4; ++cc) {
            int c = t + cc*256;
            int row = c >> 3;
            int ko = (c & 7) * 8;
            *(float4*)&Als[row][ko] = *(const float4*)(Ash + (size_t)(r0+row)*K + kk + ko);
        }
        if (!TRB) {
            #pragma unroll
            for (int cc = 0; cc < 4; ++cc) {
                int c = t + cc*256;
                int row = c >> 3;
                int ko = (c & 7) * 8;
                *(float4*)&Bls[row][ko] = *(const float4*)(B + (size_t)(n0+row)*K + kk + ko);
            }
        } else {
            int pi  = t & 31;
            int nc8 = t >> 5;
            int hk = kk + 2*pi;
            const ushort* g0 = B + (size_t)hk*NC + n0 + nc8*16;
            const ushort* g1 = g0 + NC;
            float4 v0a = *(const float4*)g0;
            float4 v0b = *(const float4*)(g0 + 8);
            float4 v1a = *(const float4*)g1;
            float4 v1b = *(const float4*)(g1 + 8);
            const ushort* pa = (const ushort*)&v0a;
            const ushort* pb = (const ushort*)&v0b;
            const ushort* qa = (const ushort*)&v1a;
            const ushort* qb = (const ushort*)&v1b;
            #pragma unroll
            for (int e = 0; e < 8; ++e) {
                *(uint*)&Bls[nc8*16 + e][2*pi]     = (uint)pa[e] | ((uint)qa[e] << 16);
                *(uint*)&Bls[nc8*16 + 8 + e][2*pi] = (uint)pb[e] | ((uint)qb[e] << 16);
            }
        }
        __syncthreads();
        #pragma unroll
        for (int ks = 0; ks < 64; ks += 32) {
            bf16x8 af[4], bfr[4];
            #pragma unroll
            for (int i = 0; i < 4; ++i)
                af[i] = *(const bf16x8*)&Als[wr*64 + i*16 + c16][ks + q*8];
            #pragma unroll
            for (int j = 0; j < 4; ++j)
                bfr[j] = *(const bf16x8*)&Bls[wc*64 + j*16 + c16][ks + q*8];
            #pragma unroll
            for (int i = 0; i < 4; ++i)
                #pragma unroll
                for (int j = 0; j < 4; ++j)
                    acc[i][j] = __builtin_amdgcn_mfma_f32_16x16x32_bf16(af[i], bfr[j], acc[i][j], 0, 0, 0);
        }
        __syncthreads();
    }
    #pragma unroll
    for (int i = 0; i < 4; ++i) {
        int rowb = r0 + wr*64 + i*16 + q*4;
        #pragma unroll
        for (int j = 0; j < 4; ++j) {
            int col = n0 + wc*64 + j*16 + c16;
            #pragma unroll
            for (int r = 0; r < 4; ++r)
                outp[(size_t)(rowb + r)*NC + col] = f2bf(acc[i][j][r]);
        }
    }
}

// ---------------------------------------------------------------------------
// F1: single-pass online softmax-over-b stats for t1,t2. Stores m and 1/d.
// ---------------------------------------------------------------------------
__global__ __launch_bounds__(1024) void kF1_stats(
    const ushort* __restrict__ t1, const ushort* __restrict__ t2,
    float* __restrict__ m1, float* __restrict__ rd1,
    float* __restrict__ m2, float* __restrict__ rd2)
{
    int s = blockIdx.x;
    int t = threadIdx.x;
    int hp = t & 127;
    int bq = t >> 7;
    int h0 = hp*2;
    const size_t str = (size_t)SIGx*HIDx;
    size_t base = (size_t)(bq*32)*str + (size_t)s*HIDx + h0;
    const ushort* p1 = t1 + base;
    const ushort* p2 = t2 + base;

    float m1a=-3.0e38f, d1a=0.0f, m1b=-3.0e38f, d1b=0.0f;
    float m2a=-3.0e38f, d2a=0.0f, m2b=-3.0e38f, d2b=0.0f;
    #pragma unroll 4
    for (int i = 0; i < 32; ++i) {
        uint u1 = *(const uint*)(p1 + (size_t)i*str);
        uint u2 = *(const uint*)(p2 + (size_t)i*str);
        float va = __uint_as_float(u1 << 16);
        float vb = __uint_as_float(u1 & 0xffff0000u);
        float wa = __uint_as_float(u2 << 16);
        float wb = __uint_as_float(u2 & 0xffff0000u);
        float mn;
        mn = fmaxf(m1a, va); d1a = d1a*__expf(m1a-mn) + __expf(va-mn); m1a = mn;
        mn = fmaxf(m1b, vb); d1b = d1b*__expf(m1b-mn) + __expf(vb-mn); m1b = mn;
        mn = fmaxf(m2a, wa); d2a = d2a*__expf(m2a-mn) + __expf(wa-mn); m2a = mn;
        mn = fmaxf(m2b, wb); d2b = d2b*__expf(m2b-mn) + __expf(wb-mn); m2b = mn;
    }

    __shared__ float pm1[8][256], pd1[8][256], pm2[8][256], pd2[8][256];
    pm1[bq][h0] = m1a; pd1[bq][h0] = d1a;
    pm1[bq][h0+1] = m1b; pd1[bq][h0+1] = d1b;
    pm2[bq][h0] = m2a; pd2[bq][h0] = d2a;
    pm2[bq][h0+1] = m2b; pd2[bq][h0+1] = d2b;
    __syncthreads();

    if (t < 256) {
        int h = t;
        float m = -3.0e38f, d = 0.0f;
        #pragma unroll
        for (int j = 0; j < 8; ++j) {
            float mm = pm1[j][h], dd = pd1[j][h];
            float mn = fmaxf(m, mm);
            d = d*__expf(m-mn) + dd*__expf(mm-mn);
            m = mn;
        }
        size_t o = (size_t)s*HIDx + h;
        m1[o] = m; rd1[o] = 1.0f/d;
    } else if (t < 512) {
        int h = t - 256;
        float m = -3.0e38f, d = 0.0f;
        #pragma unroll
        for (int j = 0; j < 8; ++j) {
            float mm = pm2[j][h], dd = pd2[j][h];
            float mn = fmaxf(m, mm);
            d = d*__expf(m-mn) + dd*__expf(mm-mn);
            m = mn;
        }
        size_t o = (size_t)s*HIDx + h;
        m2[o] = m; rd2[o] = 1.0f/d;
    }
}

// ---------------------------------------------------------------------------
// F2: sig[b,s] = sum_h exp(t1-m1)*rd1 + exp(t2-m2)*rd2
// ---------------------------------------------------------------------------
__global__ __launch_bounds__(256) void kF2_sig(
    const __hip_bfloat16* __restrict__ t1, const __hip_bfloat16* __restrict__ t2,
    const float* __restrict__ m1, const float* __restrict__ rd1,
    const float* __restrict__ m2, const float* __restrict__ rd2,
    float* __restrict__ sig)
{
    int s = blockIdx.x;
    int b = blockIdx.y;
    int h = threadIdx.x;
    size_t sh = (size_t)s*HIDx + h;
    size_t tb = ((size_t)b*SIGx + s)*HIDx + h;
    float v = __expf(loadT(&t1[tb]) - m1[sh]) * rd1[sh]
            + __expf(loadT(&t2[tb]) - m2[sh]) * rd2[sh];
    __shared__ float red[256];
    red[h] = v;
    __syncthreads();
    for (int st = 128; st > 0; st >>= 1) {
        if (h < st) red[h] += red[h+st];
        __syncthreads();
    }
    if (h == 0) sig[(size_t)b*SIGx + s] = red[0];
}

// ---------------------------------------------------------------------------
// G: out[b,:] = softmax(sig[b,:] @ fcf_w.T + fcf_b)
// ---------------------------------------------------------------------------
__global__ __launch_bounds__(256) void kG_out(
    const float* __restrict__ sig, const float* __restrict__ fw,
    const float* __restrict__ fb, float* __restrict__ out)
{
    int b = blockIdx.x;
    int tid = threadIdx.x;
    __shared__ float red[256];
    __shared__ float logits[OUTx];
    float sv = sig[(size_t)b*SIGx + tid];
    for (int o = 0; o < OUTx; ++o) {
        red[tid] = sv * fw[o*SIGx + tid];
        __syncthreads();
        for (int st = 128; st > 0; st >>= 1) {
            if (tid < st) red[tid] += red[tid+st];
            __syncthreads();
        }
        if (tid == 0) logits[o] = red[0] + fb[o];
        __syncthreads();
    }
    if (tid == 0) {
        float mx = logits[0];
        for (int o = 1; o < OUTx; ++o) mx = fmaxf(mx, logits[o]);
        float dd = 0.0f; float e[OUTx];
        for (int o = 0; o < OUTx; ++o) { e[o] = expf(logits[o]-mx); dd += e[o]; }
        float inv = 1.0f/dd;
        for (int o = 0; o < OUTx; ++o) out[(size_t)b*OUTx + o] = e[o]*inv;
    }
}

// ---------------------------------------------------------------------------
static inline size_t alignup(size_t b) { return (b + 255) & ~(size_t)255; }

extern "C" void kernel_launch(void* const* d_in, const int* in_sizes, int n_in,
                              void* d_out, int out_size, void* d_ws, size_t ws_size,
                              hipStream_t stream)
{
    const float* x   = (const float*)d_in[0];
    // d_in[1] = unif -- dead
    const float* z   = (const float*)d_in[2];
    const float* mg  = (const float*)d_in[3];
    const float* w1  = (const float*)d_in[4];
    const float* b1  = (const float*)d_in[5];
    const float* w2  = (const float*)d_in[6];
    const float* b2  = (const float*)d_in[7];
    const float* c1  = (const float*)d_in[8];
    const float* c2  = (const float*)d_in[9];
    const float* fw  = (const float*)d_in[10];
    const float* fbv = (const float*)d_in[11];
    float* out = (float*)d_out;
    float* flp = out + (size_t)Bx*OUTx;
    (void)in_sizes; (void)n_in; (void)out_size;

    char* ws = (char*)d_ws;
    size_t off = 0;
    auto alloc = [&](size_t bytes) -> char* {
        char* p = ws + off; off += alignup(bytes); return p;
    };
    float*  feat = (float*)alloc((size_t)Bx*Nx*3*4);
    ushort* c1h  = (ushort*)alloc((size_t)SIGx*Nx*2);
    ushort* c2h  = (ushort*)alloc((size_t)SIGx*Nx*2);
    ushort* w2t  = (ushort*)alloc((size_t)HIDx*HIDx*2);
    ushort* t1   = (ushort*)alloc((size_t)Bx*SIGx*HIDx*2);
    ushort* t2   = (ushort*)alloc((size_t)Bx*SIGx*HIDx*2);
    float*  m1   = (float*)alloc((size_t)SIGx*HIDx*4);
    float*  d1   = (float*)alloc((size_t)SIGx*HIDx*4);
    float*  m2   = (float*)alloc((size_t)SIGx*HIDx*4);
    float*  d2   = (float*)alloc((size_t)SIGx*HIDx*4);
    float*  sig  = (float*)alloc((size_t)Bx*SIGx*4);
    size_t fixed = off;

    int BC = 1;
    for (int c = Bx; c >= 1; c >>= 1) {
        if (fixed + 2*alignup((size_t)c*HIDx*Nx*2) <= ws_size) { BC = c; break; }
    }
    ushort* P1 = (ushort*)alloc((size_t)BC*HIDx*Nx*2);   // h2t
    ushort* P2 = (ushort*)alloc((size_t)BC*HIDx*Nx*2);   // s1t / s2t

    hipLaunchKernelGGL(kA_sample, dim3(Bx), dim3(Nx), 0, stream, x, z, mg, feat, flp);
    hipLaunchKernelGGL(kPrep, dim3(512), dim3(256), 0, stream, c1, c2, w2, c1h, c2h, w2t);

    const int nch = Bx / BC;
    for (int c = 0; c < nch; ++c) {
        int b0 = c * BC;
        const float* featL = feat + (size_t)b0*Nx*3;
        ushort* t1L = t1 + (size_t)b0*SIGx*HIDx;
        ushort* t2L = t2 + (size_t)b0*SIGx*HIDx;
        // s1t = relu((feat@gc1_w)^T * adj + b1)   -- A generated in-kernel
        hipLaunchKernelGGL(kGadjT<true>, dim3(4, BC), dim3(256), 0, stream,
                           (const ushort*)nullptr, featL, w1, b1, P2);
        // t1 = c1h @ s1
        hipLaunchKernelGGL((kGstd<512,256,false>), dim3(4, BC), dim3(256), 0, stream, c1h, P2, t1L);
        // h2t = w2t-GEMM vs s1t (transposed staging)
        hipLaunchKernelGGL((kGstd<256,512,true>), dim3(8, BC), dim3(256), 0, stream, w2t, P2, P1);
        // s2t = relu(h2t * adj + b2)   -- A loaded from P1
        hipLaunchKernelGGL(kGadjT<false>, dim3(4, BC), dim3(256), 0, stream,
                           (const ushort*)P1, featL, w1, b2, P2);
        // t2 = c2h @ s2
        hipLaunchKernelGGL((kGstd<512,256,false>), dim3(4, BC), dim3(256), 0, stream, c2h, P2, t2L);
    }

    hipLaunchKernelGGL(kF1_stats, dim3(SIGx), dim3(1024), 0, stream,
                       t1, t2, m1, d1, m2, d2);
    hipLaunchKernelGGL(kF2_sig, dim3(SIGx, Bx), dim3(256), 0, stream,
                       (const __hip_bfloat16*)t1, (const __hip_bfloat16*)t2, m1, d1, m2, d2, sig);
    hipLaunchKernelGGL(kG_out, dim3(Bx), dim3(256), 0, stream, sig, fw, fbv, out);
}

// Round 7
// 457.189 us; speedup vs baseline: 1.1509x; 1.1509x over previous
//
#include <hip/hip_runtime.h>
#include <hip/hip_bf16.h>
#include <math.h>

#define Bx   256
#define Nx   512
#define SIGx 256
#define HIDx 256
#define OUTx 10
#define Hx   256

#define LDAP 72   // LDS k-stride for GEMM tiles

typedef __attribute__((ext_vector_type(8))) short bf16x8;
typedef __attribute__((ext_vector_type(4))) float f32x4;

__device__ inline ushort f2bf(float v) {
    __hip_bfloat16 h = __float2bfloat16(v);
    return *reinterpret_cast<ushort*>(&h);
}
__device__ inline float loadT(const __hip_bfloat16* p) { return __bfloat162float(*p); }

// ---------------------------------------------------------------------------
// Kernel A: sampling stage (mixture fields constant over m => unif dead).
// ---------------------------------------------------------------------------
__global__ __launch_bounds__(512) void kA_sample(
    const float* __restrict__ x, const float* __restrict__ z,
    const float* __restrict__ mg, float* __restrict__ feat,
    float* __restrict__ flp)
{
    int b = blockIdx.x;
    int n = threadIdx.x;
    int g = n >> 5;
    float mux = mg[g*6+1];
    float muy = mg[g*6+2];
    float sxv = expf(mg[g*6+3]);
    float syv = expf(mg[g*6+4]);
    float rho = tanhf(mg[g*6+5]);
    float z1 = z[((size_t)b*Nx + n)*2 + 0];
    float z2 = z[((size_t)b*Nx + n)*2 + 1];
    float omr2 = 1.0f - rho*rho;
    float xs = mux + sxv*z1;
    float ys = muy + syv*(rho*z1 + sqrtf(omr2)*z2);
    float dx = xs - mux, dy = ys - muy;
    float quad = (dx*dx/(sxv*sxv) - 2.0f*rho*dx*dy/(sxv*syv) + dy*dy/(syv*syv)) / omr2;
    float logprob = -1.8378770664093453f - logf(sxv*syv) - 0.5f*logf(omr2) - 0.5f*quad;
    float lx = tanhf(xs), ly = tanhf(ys);
    int px = (int)truncf(0.5f*(lx+1.0f)*(float)Hx - 0.1f);
    int py = (int)truncf(0.5f*(ly+1.0f)*(float)Hx - 0.1f);
    px = px < 0 ? 0 : (px > Hx-1 ? Hx-1 : px);
    py = py < 0 ? 0 : (py > Hx-1 ? Hx-1 : py);
    float pv = x[(size_t)b*Hx*Hx + (size_t)px*Hx + py];
    size_t fo = ((size_t)b*Nx + n)*3;
    feat[fo+0] = pv; feat[fo+1] = lx; feat[fo+2] = ly;

    __shared__ float red[512];
    red[n] = logprob;
    __syncthreads();
    for (int st = 256; st > 0; st >>= 1) {
        if (n < st) red[n] += red[n+st];
        __syncthreads();
    }
    if (n == 0) flp[b] = red[0];
}

// ---------------------------------------------------------------------------
// Prep: c1,c2 -> bf16; w2 -> w2t bf16 (transposed).
// ---------------------------------------------------------------------------
__global__ __launch_bounds__(256) void kPrep(
    const float* __restrict__ c1, const float* __restrict__ c2,
    const float* __restrict__ w2,
    ushort* __restrict__ c1h, ushort* __restrict__ c2h, ushort* __restrict__ w2t)
{
    int idx = blockIdx.x*256 + threadIdx.x;
    if (idx < SIGx*Nx) {
        c1h[idx] = f2bf(c1[idx]);
        c2h[idx] = f2bf(c2[idx]);
    }
    if (idx < HIDx*HIDx) {
        int i = idx >> 8, j = idx & 255;
        w2t[idx] = f2bf(w2[j*HIDx + i]);
    }
}

// ===========================================================================
// kFuse1: per b -- generate adj (bf16, materialized for pass 2), accumulate
// G[c][n] = sum_m featT[c][m]*adj[m][n] in fp32, then rank-3 epilogue
// s1t[h][n] = relu(w1[0][h]*G0 + w1[1][h]*G1 + w1[2][h]*G2 + b1[h]).
// This replaces the whole pass-1 GEMM (s1 = relu(adj@(feat@W1)+b1)) exactly
// by associativity. Block = 512 threads (one per column n), grid = BC.
// ===========================================================================
__global__ __launch_bounds__(512) void kFuse1(
    const float* __restrict__ featL, const float* __restrict__ w1,
    const float* __restrict__ b1,
    ushort* __restrict__ adjAll, ushort* __restrict__ s1tAll)
{
    int b = blockIdx.x;
    const float* fb = featL + (size_t)b*Nx*3;
    ushort* adj = adjAll + (size_t)b*Nx*Nx;
    ushort* s1t = s1tAll + (size_t)b*HIDx*Nx;

    __shared__ float fpv[Nx], flx[Nx], fly[Nx], fH[Nx];
    __shared__ float w1s[3*HIDx], b1s[HIDx];

    int t = threadIdx.x;   // 512 = one per n
    {
        float pv = fb[t*3+0], lx = fb[t*3+1], ly = fb[t*3+2];
        fpv[t] = pv; flx[t] = lx; fly[t] = ly;
        fH[t] = fmaf(0.5f*lx, lx, fmaf(0.5f*ly, ly, 1.0f));
    }
    for (int i = t; i < 3*HIDx; i += 512) w1s[i] = w1[i];
    if (t < HIDx) b1s[t] = b1[t];
    __syncthreads();

    float xn = flx[t], yn = fly[t];
    float cn = fmaf(0.5f*xn, xn, 0.5f*yn*yn);
    float G0 = 0.0f, G1 = 0.0f, G2 = 0.0f;

    #pragma unroll 8
    for (int m = 0; m < Nx; ++m) {
        float s = fmaf(-yn, fly[m], fmaf(-xn, flx[m], fH[m] + cn));
        float a = __builtin_amdgcn_rcpf(s);
        adj[(size_t)m*Nx + t] = f2bf(a);
        G0 = fmaf(a, fpv[m], G0);
        G1 = fmaf(a, flx[m], G1);
        G2 = fmaf(a, fly[m], G2);
    }

    #pragma unroll 4
    for (int h = 0; h < HIDx; ++h) {
        float v = fmaf(G0, w1s[h], fmaf(G1, w1s[HIDx+h], fmaf(G2, w1s[2*HIDx+h], b1s[h])));
        s1t[(size_t)h*Nx + t] = f2bf(fmaxf(v, 0.0f));
    }
}

// ===========================================================================
// kGemmAdj (pass 2): C[h][n] = sum_m h2t[h][m] * adj[m][n], bias+relu.
// adj symmetric -> B[col=n][k=m] = adj rows (coalesced). 128x128 tile,
// acc 4x4 (64 regs/lane -> 3 waves/SIMD). Grid (8 = 2rt x 4ct, BC).
// ===========================================================================
__global__ __launch_bounds__(256) void kGemmAdj(
    const ushort* __restrict__ Aall, const ushort* __restrict__ adjAll,
    const float* __restrict__ bias, ushort* __restrict__ outAll)
{
    int b  = blockIdx.y;
    int rt = blockIdx.x >> 2;
    int ct = blockIdx.x & 3;
    const ushort* A = Aall + (size_t)b*HIDx*Nx;
    const ushort* Badj = adjAll + (size_t)b*Nx*Nx;
    ushort* outp = outAll + (size_t)b*HIDx*Nx;

    __shared__ short Als[128][LDAP];
    __shared__ short Bls[128][LDAP];
    int t = threadIdx.x;
    int lane = t & 63, wave = t >> 6;
    int wr = wave >> 1, wc = wave & 1;
    int q = lane >> 4, c16 = lane & 15;
    int r0 = rt*128, n0 = ct*128;
    f32x4 acc[4][4] = {};

    for (int kk = 0; kk < Nx; kk += 64) {
        #pragma unroll
        for (int cc = 0; cc < 4; ++cc) {
            int c = t + cc*256;
            int row = c >> 3;
            int ko = (c & 7) * 8;
            *(float4*)&Als[row][ko] = *(const float4*)(A + (size_t)(r0+row)*Nx + kk + ko);
            *(float4*)&Bls[row][ko] = *(const float4*)(Badj + (size_t)(n0+row)*Nx + kk + ko);
        }
        __syncthreads();
        #pragma unroll
        for (int ks = 0; ks < 64; ks += 32) {
            bf16x8 af[4], bfr[4];
            #pragma unroll
            for (int i = 0; i < 4; ++i)
                af[i] = *(const bf16x8*)&Als[wr*64 + i*16 + c16][ks + q*8];
            #pragma unroll
            for (int j = 0; j < 4; ++j)
                bfr[j] = *(const bf16x8*)&Bls[wc*64 + j*16 + c16][ks + q*8];
            #pragma unroll
            for (int i = 0; i < 4; ++i)
                #pragma unroll
                for (int j = 0; j < 4; ++j)
                    acc[i][j] = __builtin_amdgcn_mfma_f32_16x16x32_bf16(af[i], bfr[j], acc[i][j], 0, 0, 0);
        }
        __syncthreads();
    }
    #pragma unroll
    for (int i = 0; i < 4; ++i) {
        int rowb = r0 + wr*64 + i*16 + q*4;
        #pragma unroll
        for (int j = 0; j < 4; ++j) {
            int col = n0 + wc*64 + j*16 + c16;
            #pragma unroll
            for (int r = 0; r < 4; ++r) {
                float v = fmaxf(acc[i][j][r] + bias[rowb + r], 0.0f);
                outp[(size_t)(rowb + r)*Nx + col] = f2bf(v);
            }
        }
    }
}

// ---------------------------------------------------------------------------
// kGstd: C[row][col] = sum_k Ash[row][k] * B[k][col]  (A shared, B per-b)
// ---------------------------------------------------------------------------
template<int K, int NC, bool TRB>
__global__ __launch_bounds__(256) void kGstd(
    const ushort* __restrict__ Ash, const ushort* __restrict__ Ball,
    ushort* __restrict__ outAll)
{
    constexpr int CT = NC / 128;
    int b  = blockIdx.y;
    int rt = blockIdx.x / CT;
    int ct = blockIdx.x % CT;
    const ushort* B = Ball + (size_t)b*HIDx*Nx;
    ushort* outp = outAll + (size_t)b*HIDx*NC;

    __shared__ short Als[128][LDAP];
    __shared__ short Bls[128][LDAP];
    int t = threadIdx.x;
    int lane = t & 63, wave = t >> 6;
    int wr = wave >> 1, wc = wave & 1;
    int q = lane >> 4, c16 = lane & 15;
    int r0 = rt*128, n0 = ct*128;
    f32x4 acc[4][4] = {};

    for (int kk = 0; kk < K; kk += 64) {
        #pragma unroll
        for (int cc = 0; cc < 4; ++cc) {
            int c = t + cc*256;
            int row = c >> 3;
            int ko = (c & 7) * 8;
            *(float4*)&Als[row][ko] = *(const float4*)(Ash + (size_t)(r0+row)*K + kk + ko);
        }
        if (!TRB) {
            #pragma unroll
            for (int cc = 0; cc < 4; ++cc) {
                int c = t + cc*256;
                int row = c >> 3;
                int ko = (c & 7) * 8;
                *(float4*)&Bls[row][ko] = *(const float4*)(B + (size_t)(n0+row)*K + kk + ko);
            }
        } else {
            int pi  = t & 31;
            int nc8 = t >> 5;
            int hk = kk + 2*pi;
            const ushort* g0 = B + (size_t)hk*NC + n0 + nc8*16;
            const ushort* g1 = g0 + NC;
            float4 v0a = *(const float4*)g0;
            float4 v0b = *(const float4*)(g0 + 8);
            float4 v1a = *(const float4*)g1;
            float4 v1b = *(const float4*)(g1 + 8);
            const ushort* pa = (const ushort*)&v0a;
            const ushort* pb = (const ushort*)&v0b;
            const ushort* qa = (const ushort*)&v1a;
            const ushort* qb = (const ushort*)&v1b;
            #pragma unroll
            for (int e = 0; e < 8; ++e) {
                *(uint*)&Bls[nc8*16 + e][2*pi]     = (uint)pa[e] | ((uint)qa[e] << 16);
                *(uint*)&Bls[nc8*16 + 8 + e][2*pi] = (uint)pb[e] | ((uint)qb[e] << 16);
            }
        }
        __syncthreads();
        #pragma unroll
        for (int ks = 0; ks < 64; ks += 32) {
            bf16x8 af[4], bfr[4];
            #pragma unroll
            for (int i = 0; i < 4; ++i)
                af[i] = *(const bf16x8*)&Als[wr*64 + i*16 + c16][ks + q*8];
            #pragma unroll
            for (int j = 0; j < 4; ++j)
                bfr[j] = *(const bf16x8*)&Bls[wc*64 + j*16 + c16][ks + q*8];
            #pragma unroll
            for (int i = 0; i < 4; ++i)
                #pragma unroll
                for (int j = 0; j < 4; ++j)
                    acc[i][j] = __builtin_amdgcn_mfma_f32_16x16x32_bf16(af[i], bfr[j], acc[i][j], 0, 0, 0);
        }
        __syncthreads();
    }
    #pragma unroll
    for (int i = 0; i < 4; ++i) {
        int rowb = r0 + wr*64 + i*16 + q*4;
        #pragma unroll
        for (int j = 0; j < 4; ++j) {
            int col = n0 + wc*64 + j*16 + c16;
            #pragma unroll
            for (int r = 0; r < 4; ++r)
                outp[(size_t)(rowb + r)*NC + col] = f2bf(acc[i][j][r]);
        }
    }
}

// ---------------------------------------------------------------------------
// F1: single-pass online softmax-over-b stats for t1,t2. Stores m and 1/d.
// ---------------------------------------------------------------------------
__global__ __launch_bounds__(1024) void kF1_stats(
    const ushort* __restrict__ t1, const ushort* __restrict__ t2,
    float* __restrict__ m1, float* __restrict__ rd1,
    float* __restrict__ m2, float* __restrict__ rd2)
{
    int s = blockIdx.x;
    int t = threadIdx.x;
    int hp = t & 127;
    int bq = t >> 7;
    int h0 = hp*2;
    const size_t str = (size_t)SIGx*HIDx;
    size_t base = (size_t)(bq*32)*str + (size_t)s*HIDx + h0;
    const ushort* p1 = t1 + base;
    const ushort* p2 = t2 + base;

    float m1a=-3.0e38f, d1a=0.0f, m1b=-3.0e38f, d1b=0.0f;
    float m2a=-3.0e38f, d2a=0.0f, m2b=-3.0e38f, d2b=0.0f;
    #pragma unroll 4
    for (int i = 0; i < 32; ++i) {
        uint u1 = *(const uint*)(p1 + (size_t)i*str);
        uint u2 = *(const uint*)(p2 + (size_t)i*str);
        float va = __uint_as_float(u1 << 16);
        float vb = __uint_as_float(u1 & 0xffff0000u);
        float wa = __uint_as_float(u2 << 16);
        float wb = __uint_as_float(u2 & 0xffff0000u);
        float mn;
        mn = fmaxf(m1a, va); d1a = d1a*__expf(m1a-mn) + __expf(va-mn); m1a = mn;
        mn = fmaxf(m1b, vb); d1b = d1b*__expf(m1b-mn) + __expf(vb-mn); m1b = mn;
        mn = fmaxf(m2a, wa); d2a = d2a*__expf(m2a-mn) + __expf(wa-mn); m2a = mn;
        mn = fmaxf(m2b, wb); d2b = d2b*__expf(m2b-mn) + __expf(wb-mn); m2b = mn;
    }

    __shared__ float pm1[8][256], pd1[8][256], pm2[8][256], pd2[8][256];
    pm1[bq][h0] = m1a; pd1[bq][h0] = d1a;
    pm1[bq][h0+1] = m1b; pd1[bq][h0+1] = d1b;
    pm2[bq][h0] = m2a; pd2[bq][h0] = d2a;
    pm2[bq][h0+1] = m2b; pd2[bq][h0+1] = d2b;
    __syncthreads();

    if (t < 256) {
        int h = t;
        float m = -3.0e38f, d = 0.0f;
        #pragma unroll
        for (int j = 0; j < 8; ++j) {
            float mm = pm1[j][h], dd = pd1[j][h];
            float mn = fmaxf(m, mm);
            d = d*__expf(m-mn) + dd*__expf(mm-mn);
            m = mn;
        }
        size_t o = (size_t)s*HIDx + h;
        m1[o] = m; rd1[o] = 1.0f/d;
    } else if (t < 512) {
        int h = t - 256;
        float m = -3.0e38f, d = 0.0f;
        #pragma unroll
        for (int j = 0; j < 8; ++j) {
            float mm = pm2[j][h], dd = pd2[j][h];
            float mn = fmaxf(m, mm);
            d = d*__expf(m-mn) + dd*__expf(mm-mn);
            m = mn;
        }
        size_t o = (size_t)s*HIDx + h;
        m2[o] = m; rd2[o] = 1.0f/d;
    }
}

// ---------------------------------------------------------------------------
// F2: sig[b,s] = sum_h exp(t1-m1)*rd1 + exp(t2-m2)*rd2
// ---------------------------------------------------------------------------
__global__ __launch_bounds__(256) void kF2_sig(
    const __hip_bfloat16* __restrict__ t1, const __hip_bfloat16* __restrict__ t2,
    const float* __restrict__ m1, const float* __restrict__ rd1,
    const float* __restrict__ m2, const float* __restrict__ rd2,
    float* __restrict__ sig)
{
    int s = blockIdx.x;
    int b = blockIdx.y;
    int h = threadIdx.x;
    size_t sh = (size_t)s*HIDx + h;
    size_t tb = ((size_t)b*SIGx + s)*HIDx + h;
    float v = __expf(loadT(&t1[tb]) - m1[sh]) * rd1[sh]
            + __expf(loadT(&t2[tb]) - m2[sh]) * rd2[sh];
    __shared__ float red[256];
    red[h] = v;
    __syncthreads();
    for (int st = 128; st > 0; st >>= 1) {
        if (h < st) red[h] += red[h+st];
        __syncthreads();
    }
    if (h == 0) sig[(size_t)b*SIGx + s] = red[0];
}

// ---------------------------------------------------------------------------
// G: out[b,:] = softmax(sig[b,:] @ fcf_w.T + fcf_b)
// ---------------------------------------------------------------------------
__global__ __launch_bounds__(256) void kG_out(
    const float* __restrict__ sig, const float* __restrict__ fw,
    const float* __restrict__ fb, float* __restrict__ out)
{
    int b = blockIdx.x;
    int tid = threadIdx.x;
    __shared__ float red[256];
    __shared__ float logits[OUTx];
    float sv = sig[(size_t)b*SIGx + tid];
    for (int o = 0; o < OUTx; ++o) {
        red[tid] = sv * fw[o*SIGx + tid];
        __syncthreads();
        for (int st = 128; st > 0; st >>= 1) {
            if (tid < st) red[tid] += red[tid+st];
            __syncthreads();
        }
        if (tid == 0) logits[o] = red[0] + fb[o];
        __syncthreads();
    }
    if (tid == 0) {
        float mx = logits[0];
        for (int o = 1; o < OUTx; ++o) mx = fmaxf(mx, logits[o]);
        float dd = 0.0f; float e[OUTx];
        for (int o = 0; o < OUTx; ++o) { e[o] = expf(logits[o]-mx); dd += e[o]; }
        float inv = 1.0f/dd;
        for (int o = 0; o < OUTx; ++o) out[(size_t)b*OUTx + o] = e[o]*inv;
    }
}

// ---------------------------------------------------------------------------
static inline size_t alignup(size_t b) { return (b + 255) & ~(size_t)255; }

extern "C" void kernel_launch(void* const* d_in, const int* in_sizes, int n_in,
                              void* d_out, int out_size, void* d_ws, size_t ws_size,
                              hipStream_t stream)
{
    const float* x   = (const float*)d_in[0];
    // d_in[1] = unif -- dead
    const float* z   = (const float*)d_in[2];
    const float* mg  = (const float*)d_in[3];
    const float* w1  = (const float*)d_in[4];
    const float* b1  = (const float*)d_in[5];
    const float* w2  = (const float*)d_in[6];
    const float* b2  = (const float*)d_in[7];
    const float* c1  = (const float*)d_in[8];
    const float* c2  = (const float*)d_in[9];
    const float* fw  = (const float*)d_in[10];
    const float* fbv = (const float*)d_in[11];
    float* out = (float*)d_out;
    float* flp = out + (size_t)Bx*OUTx;
    (void)in_sizes; (void)n_in; (void)out_size;

    char* ws = (char*)d_ws;
    size_t off = 0;
    auto alloc = [&](size_t bytes) -> char* {
        char* p = ws + off; off += alignup(bytes); return p;
    };
    float*  feat = (float*)alloc((size_t)Bx*Nx*3*4);
    ushort* c1h  = (ushort*)alloc((size_t)SIGx*Nx*2);
    ushort* c2h  = (ushort*)alloc((size_t)SIGx*Nx*2);
    ushort* w2t  = (ushort*)alloc((size_t)HIDx*HIDx*2);
    ushort* t1   = (ushort*)alloc((size_t)Bx*SIGx*HIDx*2);
    ushort* t2   = (ushort*)alloc((size_t)Bx*SIGx*HIDx*2);
    float*  m1   = (float*)alloc((size_t)SIGx*HIDx*4);
    float*  d1   = (float*)alloc((size_t)SIGx*HIDx*4);
    float*  m2   = (float*)alloc((size_t)SIGx*HIDx*4);
    float*  d2   = (float*)alloc((size_t)SIGx*HIDx*4);
    float*  sig  = (float*)alloc((size_t)Bx*SIGx*4);
    size_t fixed = off;

    // largest batch-chunk: adj (BCx512x512) + two ping-pong (BCx256x512) bf16
    int BC = 1;
    for (int c = Bx; c >= 1; c >>= 1) {
        size_t need = fixed + alignup((size_t)c*Nx*Nx*2)
                            + 2*alignup((size_t)c*HIDx*Nx*2);
        if (need <= ws_size) { BC = c; break; }
    }
    ushort* Padj = (ushort*)alloc((size_t)BC*Nx*Nx*2);     // adj per chunk
    ushort* P1   = (ushort*)alloc((size_t)BC*HIDx*Nx*2);   // h2t
    ushort* P2   = (ushort*)alloc((size_t)BC*HIDx*Nx*2);   // s1t / s2t

    hipLaunchKernelGGL(kA_sample, dim3(Bx), dim3(Nx), 0, stream, x, z, mg, feat, flp);
    hipLaunchKernelGGL(kPrep, dim3(512), dim3(256), 0, stream, c1, c2, w2, c1h, c2h, w2t);

    const int nch = Bx / BC;
    for (int c = 0; c < nch; ++c) {
        int b0 = c * BC;
        const float* featL = feat + (size_t)b0*Nx*3;
        ushort* t1L = t1 + (size_t)b0*SIGx*HIDx;
        ushort* t2L = t2 + (size_t)b0*SIGx*HIDx;
        // adj materialization + rank-3 pass-1 (s1t) in one kernel
        hipLaunchKernelGGL(kFuse1, dim3(BC), dim3(512), 0, stream,
                           featL, w1, b1, Padj, P2);
        // t1 = c1h @ s1
        hipLaunchKernelGGL((kGstd<512,256,false>), dim3(4, BC), dim3(256), 0, stream, c1h, P2, t1L);
        // h2t = w2t-GEMM vs s1t (transposed staging)
        hipLaunchKernelGGL((kGstd<256,512,true>), dim3(8, BC), dim3(256), 0, stream, w2t, P2, P1);
        // s2t = relu(h2t * adj + b2)  -- pure GEMM vs materialized adj
        hipLaunchKernelGGL(kGemmAdj, dim3(8, BC), dim3(256), 0, stream, P1, Padj, b2, P2);
        // t2 = c2h @ s2
        hipLaunchKernelGGL((kGstd<512,256,false>), dim3(4, BC), dim3(256), 0, stream, c2h, P2, t2L);
    }

    hipLaunchKernelGGL(kF1_stats, dim3(SIGx), dim3(1024), 0, stream,
                       t1, t2, m1, d1, m2, d2);
    hipLaunchKernelGGL(kF2_sig, dim3(SIGx, Bx), dim3(256), 0, stream,
                       (const __hip_bfloat16*)t1, (const __hip_bfloat16*)t2, m1, d1, m2, d2, sig);
    hipLaunchKernelGGL(kG_out, dim3(Bx), dim3(256), 0, stream, sig, fw, fbv, out);
}

// Round 8
// 359.632 us; speedup vs baseline: 1.4630x; 1.2713x over previous
//
#include <hip/hip_runtime.h>
#include <hip/hip_bf16.h>
#include <math.h>

#define Bx   256
#define Nx   512
#define SIGx 256
#define HIDx 256
#define OUTx 10
#define Hx   256

typedef __attribute__((ext_vector_type(4))) float f32x4;
typedef long fp8x8;          // 8 fp8 bytes = 2 VGPRs (MFMA A/B operand)
typedef unsigned char uchar;

__device__ inline ushort f2bf(float v) {
    __hip_bfloat16 h = __float2bfloat16(v);
    return *reinterpret_cast<ushort*>(&h);
}
__device__ inline float loadT(const __hip_bfloat16* p) { return __bfloat162float(*p); }
__device__ inline uchar f2fp8(float v) {
    int r = __builtin_amdgcn_cvt_pk_fp8_f32(v, 0.0f, 0, false);
    return (uchar)(r & 0xff);
}

// ---------------------------------------------------------------------------
// Kernel A: sampling stage (mixture fields constant over m => unif dead).
// ---------------------------------------------------------------------------
__global__ __launch_bounds__(512) void kA_sample(
    const float* __restrict__ x, const float* __restrict__ z,
    const float* __restrict__ mg, float* __restrict__ feat,
    float* __restrict__ flp)
{
    int b = blockIdx.x;
    int n = threadIdx.x;
    int g = n >> 5;
    float mux = mg[g*6+1];
    float muy = mg[g*6+2];
    float sxv = expf(mg[g*6+3]);
    float syv = expf(mg[g*6+4]);
    float rho = tanhf(mg[g*6+5]);
    float z1 = z[((size_t)b*Nx + n)*2 + 0];
    float z2 = z[((size_t)b*Nx + n)*2 + 1];
    float omr2 = 1.0f - rho*rho;
    float xs = mux + sxv*z1;
    float ys = muy + syv*(rho*z1 + sqrtf(omr2)*z2);
    float dx = xs - mux, dy = ys - muy;
    float quad = (dx*dx/(sxv*sxv) - 2.0f*rho*dx*dy/(sxv*syv) + dy*dy/(syv*syv)) / omr2;
    float logprob = -1.8378770664093453f - logf(sxv*syv) - 0.5f*logf(omr2) - 0.5f*quad;
    float lx = tanhf(xs), ly = tanhf(ys);
    int px = (int)truncf(0.5f*(lx+1.0f)*(float)Hx - 0.1f);
    int py = (int)truncf(0.5f*(ly+1.0f)*(float)Hx - 0.1f);
    px = px < 0 ? 0 : (px > Hx-1 ? Hx-1 : px);
    py = py < 0 ? 0 : (py > Hx-1 ? Hx-1 : py);
    float pv = x[(size_t)b*Hx*Hx + (size_t)px*Hx + py];
    size_t fo = ((size_t)b*Nx + n)*3;
    feat[fo+0] = pv; feat[fo+1] = lx; feat[fo+2] = ly;

    __shared__ float red[512];
    red[n] = logprob;
    __syncthreads();
    for (int st = 256; st > 0; st >>= 1) {
        if (n < st) red[n] += red[n+st];
        __syncthreads();
    }
    if (n == 0) flp[b] = red[0];
}

// ---------------------------------------------------------------------------
// Prep: c1,c2 -> fp8 (x16 scale); w2 -> w2t fp8 (x16, transposed).
// ---------------------------------------------------------------------------
__global__ __launch_bounds__(256) void kPrep(
    const float* __restrict__ c1, const float* __restrict__ c2,
    const float* __restrict__ w2,
    uchar* __restrict__ c1q, uchar* __restrict__ c2q, uchar* __restrict__ w2tq)
{
    int idx = blockIdx.x*256 + threadIdx.x;
    if (idx < SIGx*Nx) {
        c1q[idx] = f2fp8(16.0f * c1[idx]);
        c2q[idx] = f2fp8(16.0f * c2[idx]);
    }
    if (idx < HIDx*HIDx) {
        int i = idx >> 8, j = idx & 255;
        w2tq[idx] = f2fp8(16.0f * w2[j*HIDx + i]);
    }
}

// ===========================================================================
// kFuse1: per b -- generate adj (fp8, materialized), accumulate
// G[c][n] = sum_m featT[c][m]*adj[m][n] fp32, rank-3 epilogue
// s1t[h][n] = relu(w1[.][h].G + b1[h]) -> fp8.  Block 512 thr (one per n).
// ===========================================================================
__global__ __launch_bounds__(512) void kFuse1(
    const float* __restrict__ featL, const float* __restrict__ w1,
    const float* __restrict__ b1,
    uchar* __restrict__ adjAll, uchar* __restrict__ s1tAll)
{
    int b = blockIdx.x;
    const float* fb = featL + (size_t)b*Nx*3;
    uchar* adj = adjAll + (size_t)b*Nx*Nx;
    uchar* s1t = s1tAll + (size_t)b*HIDx*Nx;

    __shared__ float fpv[Nx], flx[Nx], fly[Nx], fH[Nx];
    __shared__ float w1s[3*HIDx], b1s[HIDx];

    int t = threadIdx.x;
    {
        float pv = fb[t*3+0], lx = fb[t*3+1], ly = fb[t*3+2];
        fpv[t] = pv; flx[t] = lx; fly[t] = ly;
        fH[t] = fmaf(0.5f*lx, lx, fmaf(0.5f*ly, ly, 1.0f));
    }
    for (int i = t; i < 3*HIDx; i += 512) w1s[i] = w1[i];
    if (t < HIDx) b1s[t] = b1[t];
    __syncthreads();

    float xn = flx[t], yn = fly[t];
    float cn = fmaf(0.5f*xn, xn, 0.5f*yn*yn);
    float G0 = 0.0f, G1 = 0.0f, G2 = 0.0f;

    #pragma unroll 8
    for (int m = 0; m < Nx; ++m) {
        float s = fmaf(-yn, fly[m], fmaf(-xn, flx[m], fH[m] + cn));
        float a = __builtin_amdgcn_rcpf(s);
        adj[(size_t)m*Nx + t] = f2fp8(a);
        G0 = fmaf(a, fpv[m], G0);
        G1 = fmaf(a, flx[m], G1);
        G2 = fmaf(a, fly[m], G2);
    }

    #pragma unroll 4
    for (int h = 0; h < HIDx; ++h) {
        float v = fmaf(G0, w1s[h], fmaf(G1, w1s[HIDx+h], fmaf(G2, w1s[2*HIDx+h], b1s[h])));
        v = fmaxf(v, 0.0f);
        s1t[(size_t)h*Nx + t] = f2fp8(fminf(v, 448.0f));
    }
}

// ===========================================================================
// kGemmAdjQ (pass 2): s2t[h][n] = relu(sum_m h2t[h][m]*adj[m][n] + b2[h]),
// all fp8; output scaled x0.25 (headroom), compensated in t2 epilogue.
// 128x128 tile, acc 4x4. Grid (8 = 2rt x 4ct, BC).
// ===========================================================================
__global__ __launch_bounds__(256) void kGemmAdjQ(
    const uchar* __restrict__ Aall, const uchar* __restrict__ adjAll,
    const float* __restrict__ bias, uchar* __restrict__ outAll)
{
    int b  = blockIdx.y;
    int rt = blockIdx.x >> 2;
    int ct = blockIdx.x & 3;
    const uchar* A = Aall + (size_t)b*HIDx*Nx;
    const uchar* Badj = adjAll + (size_t)b*Nx*Nx;
    uchar* outp = outAll + (size_t)b*HIDx*Nx;

    __shared__ uchar Als[128][80];
    __shared__ uchar Bls[128][80];
    int t = threadIdx.x;
    int lane = t & 63, wave = t >> 6;
    int wr = wave >> 1, wc = wave & 1;
    int q = lane >> 4, c16 = lane & 15;
    int r0 = rt*128, n0 = ct*128;
    f32x4 acc[4][4] = {};

    for (int kk = 0; kk < Nx; kk += 64) {
        #pragma unroll
        for (int cc = 0; cc < 2; ++cc) {
            int c = t + cc*256;
            int row = c >> 2;
            int ko = (c & 3) * 16;
            *(float4*)&Als[row][ko] = *(const float4*)(A + (size_t)(r0+row)*Nx + kk + ko);
            *(float4*)&Bls[row][ko] = *(const float4*)(Badj + (size_t)(n0+row)*Nx + kk + ko);
        }
        __syncthreads();
        #pragma unroll
        for (int ks = 0; ks < 64; ks += 32) {
            fp8x8 af[4], bfr[4];
            #pragma unroll
            for (int i = 0; i < 4; ++i)
                af[i] = *(const fp8x8*)&Als[wr*64 + i*16 + c16][ks + q*8];
            #pragma unroll
            for (int j = 0; j < 4; ++j)
                bfr[j] = *(const fp8x8*)&Bls[wc*64 + j*16 + c16][ks + q*8];
            #pragma unroll
            for (int i = 0; i < 4; ++i)
                #pragma unroll
                for (int j = 0; j < 4; ++j)
                    acc[i][j] = __builtin_amdgcn_mfma_f32_16x16x32_fp8_fp8(af[i], bfr[j], acc[i][j], 0, 0, 0);
        }
        __syncthreads();
    }
    #pragma unroll
    for (int i = 0; i < 4; ++i) {
        int rowb = r0 + wr*64 + i*16 + q*4;
        #pragma unroll
        for (int j = 0; j < 4; ++j) {
            int col = n0 + wc*64 + j*16 + c16;
            #pragma unroll
            for (int r = 0; r < 4; ++r) {
                float v = fmaxf(acc[i][j][r] + bias[rowb + r], 0.0f) * 0.25f;
                outp[(size_t)(rowb + r)*Nx + col] = f2fp8(fminf(v, 448.0f));
            }
        }
    }
}

// ---------------------------------------------------------------------------
// kGstdQ: C[row][col] = oscale * sum_k A[row][k]*B[k][col], fp8 inputs.
// OUT8=false -> bf16 out (t buffers); OUT8=true -> fp8 out (h2t).
// TRB=true stages B from k-major layout with on-the-fly transpose.
// ---------------------------------------------------------------------------
template<int K, int NC, bool TRB, bool OUT8>
__global__ __launch_bounds__(256) void kGstdQ(
    const uchar* __restrict__ Ash, const uchar* __restrict__ Ball,
    void* __restrict__ outAll, float oscale)
{
    constexpr int CT = NC / 128;
    int b  = blockIdx.y;
    int rt = blockIdx.x / CT;
    int ct = blockIdx.x % CT;
    const uchar* B = Ball + (size_t)b*HIDx*Nx;

    __shared__ uchar Als[128][80];
    __shared__ uchar Bls[128][80];
    int t = threadIdx.x;
    int lane = t & 63, wave = t >> 6;
    int wr = wave >> 1, wc = wave & 1;
    int q = lane >> 4, c16 = lane & 15;
    int r0 = rt*128, n0 = ct*128;
    f32x4 acc[4][4] = {};

    for (int kk = 0; kk < K; kk += 64) {
        #pragma unroll
        for (int cc = 0; cc < 2; ++cc) {
            int c = t + cc*256;
            int row = c >> 2;
            int ko = (c & 3) * 16;
            *(float4*)&Als[row][ko] = *(const float4*)(Ash + (size_t)(r0+row)*K + kk + ko);
        }
        if (!TRB) {
            #pragma unroll
            for (int cc = 0; cc < 2; ++cc) {
                int c = t + cc*256;
                int row = c >> 2;
                int ko = (c & 3) * 16;
                *(float4*)&Bls[row][ko] = *(const float4*)(B + (size_t)(n0+row)*K + kk + ko);
            }
        } else {
            int pi  = t & 31;          // k-pair within 64-k tile
            int nc8 = t >> 5;          // 8 col-groups of 16
            int hk = kk + 2*pi;
            const uchar* g0 = B + (size_t)hk*NC + n0 + nc8*16;
            const uchar* g1 = g0 + NC;
            float4 v0 = *(const float4*)g0;
            float4 v1 = *(const float4*)g1;
            const uchar* pa = (const uchar*)&v0;
            const uchar* qa = (const uchar*)&v1;
            #pragma unroll
            for (int e = 0; e < 16; ++e)
                *(ushort*)&Bls[nc8*16 + e][2*pi] = (ushort)pa[e] | ((ushort)qa[e] << 8);
        }
        __syncthreads();
        #pragma unroll
        for (int ks = 0; ks < 64; ks += 32) {
            fp8x8 af[4], bfr[4];
            #pragma unroll
            for (int i = 0; i < 4; ++i)
                af[i] = *(const fp8x8*)&Als[wr*64 + i*16 + c16][ks + q*8];
            #pragma unroll
            for (int j = 0; j < 4; ++j)
                bfr[j] = *(const fp8x8*)&Bls[wc*64 + j*16 + c16][ks + q*8];
            #pragma unroll
            for (int i = 0; i < 4; ++i)
                #pragma unroll
                for (int j = 0; j < 4; ++j)
                    acc[i][j] = __builtin_amdgcn_mfma_f32_16x16x32_fp8_fp8(af[i], bfr[j], acc[i][j], 0, 0, 0);
        }
        __syncthreads();
    }
    #pragma unroll
    for (int i = 0; i < 4; ++i) {
        int rowb = r0 + wr*64 + i*16 + q*4;
        #pragma unroll
        for (int j = 0; j < 4; ++j) {
            int col = n0 + wc*64 + j*16 + c16;
            #pragma unroll
            for (int r = 0; r < 4; ++r) {
                float v = acc[i][j][r] * oscale;
                if (OUT8) {
                    uchar* outp = (uchar*)outAll + (size_t)b*HIDx*NC;
                    v = fminf(fmaxf(v, -448.0f), 448.0f);
                    outp[(size_t)(rowb + r)*NC + col] = f2fp8(v);
                } else {
                    ushort* outp = (ushort*)outAll + (size_t)b*HIDx*NC;
                    outp[(size_t)(rowb + r)*NC + col] = f2bf(v);
                }
            }
        }
    }
}

// ---------------------------------------------------------------------------
// F1: single-pass online softmax-over-b stats for t1,t2 (bf16). m and 1/d.
// ---------------------------------------------------------------------------
__global__ __launch_bounds__(1024) void kF1_stats(
    const ushort* __restrict__ t1, const ushort* __restrict__ t2,
    float* __restrict__ m1, float* __restrict__ rd1,
    float* __restrict__ m2, float* __restrict__ rd2)
{
    int s = blockIdx.x;
    int t = threadIdx.x;
    int hp = t & 127;
    int bq = t >> 7;
    int h0 = hp*2;
    const size_t str = (size_t)SIGx*HIDx;
    size_t base = (size_t)(bq*32)*str + (size_t)s*HIDx + h0;
    const ushort* p1 = t1 + base;
    const ushort* p2 = t2 + base;

    float m1a=-3.0e38f, d1a=0.0f, m1b=-3.0e38f, d1b=0.0f;
    float m2a=-3.0e38f, d2a=0.0f, m2b=-3.0e38f, d2b=0.0f;
    #pragma unroll 4
    for (int i = 0; i < 32; ++i) {
        uint u1 = *(const uint*)(p1 + (size_t)i*str);
        uint u2 = *(const uint*)(p2 + (size_t)i*str);
        float va = __uint_as_float(u1 << 16);
        float vb = __uint_as_float(u1 & 0xffff0000u);
        float wa = __uint_as_float(u2 << 16);
        float wb = __uint_as_float(u2 & 0xffff0000u);
        float mn;
        mn = fmaxf(m1a, va); d1a = d1a*__expf(m1a-mn) + __expf(va-mn); m1a = mn;
        mn = fmaxf(m1b, vb); d1b = d1b*__expf(m1b-mn) + __expf(vb-mn); m1b = mn;
        mn = fmaxf(m2a, wa); d2a = d2a*__expf(m2a-mn) + __expf(wa-mn); m2a = mn;
        mn = fmaxf(m2b, wb); d2b = d2b*__expf(m2b-mn) + __expf(wb-mn); m2b = mn;
    }

    __shared__ float pm1[8][256], pd1[8][256], pm2[8][256], pd2[8][256];
    pm1[bq][h0] = m1a; pd1[bq][h0] = d1a;
    pm1[bq][h0+1] = m1b; pd1[bq][h0+1] = d1b;
    pm2[bq][h0] = m2a; pd2[bq][h0] = d2a;
    pm2[bq][h0+1] = m2b; pd2[bq][h0+1] = d2b;
    __syncthreads();

    if (t < 256) {
        int h = t;
        float m = -3.0e38f, d = 0.0f;
        #pragma unroll
        for (int j = 0; j < 8; ++j) {
            float mm = pm1[j][h], dd = pd1[j][h];
            float mn = fmaxf(m, mm);
            d = d*__expf(m-mn) + dd*__expf(mm-mn);
            m = mn;
        }
        size_t o = (size_t)s*HIDx + h;
        m1[o] = m; rd1[o] = 1.0f/d;
    } else if (t < 512) {
        int h = t - 256;
        float m = -3.0e38f, d = 0.0f;
        #pragma unroll
        for (int j = 0; j < 8; ++j) {
            float mm = pm2[j][h], dd = pd2[j][h];
            float mn = fmaxf(m, mm);
            d = d*__expf(m-mn) + dd*__expf(mm-mn);
            m = mn;
        }
        size_t o = (size_t)s*HIDx + h;
        m2[o] = m; rd2[o] = 1.0f/d;
    }
}

// ---------------------------------------------------------------------------
// F2: sig[b,s] = sum_h exp(t1-m1)*rd1 + exp(t2-m2)*rd2
// ---------------------------------------------------------------------------
__global__ __launch_bounds__(256) void kF2_sig(
    const __hip_bfloat16* __restrict__ t1, const __hip_bfloat16* __restrict__ t2,
    const float* __restrict__ m1, const float* __restrict__ rd1,
    const float* __restrict__ m2, const float* __restrict__ rd2,
    float* __restrict__ sig)
{
    int s = blockIdx.x;
    int b = blockIdx.y;
    int h = threadIdx.x;
    size_t sh = (size_t)s*HIDx + h;
    size_t tb = ((size_t)b*SIGx + s)*HIDx + h;
    float v = __expf(loadT(&t1[tb]) - m1[sh]) * rd1[sh]
            + __expf(loadT(&t2[tb]) - m2[sh]) * rd2[sh];
    __shared__ float red[256];
    red[h] = v;
    __syncthreads();
    for (int st = 128; st > 0; st >>= 1) {
        if (h < st) red[h] += red[h+st];
        __syncthreads();
    }
    if (h == 0) sig[(size_t)b*SIGx + s] = red[0];
}

// ---------------------------------------------------------------------------
// G: out[b,:] = softmax(sig[b,:] @ fcf_w.T + fcf_b)
// ---------------------------------------------------------------------------
__global__ __launch_bounds__(256) void kG_out(
    const float* __restrict__ sig, const float* __restrict__ fw,
    const float* __restrict__ fb, float* __restrict__ out)
{
    int b = blockIdx.x;
    int tid = threadIdx.x;
    __shared__ float red[256];
    __shared__ float logits[OUTx];
    float sv = sig[(size_t)b*SIGx + tid];
    for (int o = 0; o < OUTx; ++o) {
        red[tid] = sv * fw[o*SIGx + tid];
        __syncthreads();
        for (int st = 128; st > 0; st >>= 1) {
            if (tid < st) red[tid] += red[tid+st];
            __syncthreads();
        }
        if (tid == 0) logits[o] = red[0] + fb[o];
        __syncthreads();
    }
    if (tid == 0) {
        float mx = logits[0];
        for (int o = 1; o < OUTx; ++o) mx = fmaxf(mx, logits[o]);
        float dd = 0.0f; float e[OUTx];
        for (int o = 0; o < OUTx; ++o) { e[o] = expf(logits[o]-mx); dd += e[o]; }
        float inv = 1.0f/dd;
        for (int o = 0; o < OUTx; ++o) out[(size_t)b*OUTx + o] = e[o]*inv;
    }
}

// ---------------------------------------------------------------------------
static inline size_t alignup(size_t b) { return (b + 255) & ~(size_t)255; }

extern "C" void kernel_launch(void* const* d_in, const int* in_sizes, int n_in,
                              void* d_out, int out_size, void* d_ws, size_t ws_size,
                              hipStream_t stream)
{
    const float* x   = (const float*)d_in[0];
    // d_in[1] = unif -- dead
    const float* z   = (const float*)d_in[2];
    const float* mg  = (const float*)d_in[3];
    const float* w1  = (const float*)d_in[4];
    const float* b1  = (const float*)d_in[5];
    const float* w2  = (const float*)d_in[6];
    const float* b2  = (const float*)d_in[7];
    const float* c1  = (const float*)d_in[8];
    const float* c2  = (const float*)d_in[9];
    const float* fw  = (const float*)d_in[10];
    const float* fbv = (const float*)d_in[11];
    float* out = (float*)d_out;
    float* flp = out + (size_t)Bx*OUTx;
    (void)in_sizes; (void)n_in; (void)out_size;

    char* ws = (char*)d_ws;
    size_t off = 0;
    auto alloc = [&](size_t bytes) -> char* {
        char* p = ws + off; off += alignup(bytes); return p;
    };
    float*  feat = (float*)alloc((size_t)Bx*Nx*3*4);
    uchar*  c1q  = (uchar*)alloc((size_t)SIGx*Nx);
    uchar*  c2q  = (uchar*)alloc((size_t)SIGx*Nx);
    uchar*  w2tq = (uchar*)alloc((size_t)HIDx*HIDx);
    ushort* t1   = (ushort*)alloc((size_t)Bx*SIGx*HIDx*2);
    ushort* t2   = (ushort*)alloc((size_t)Bx*SIGx*HIDx*2);
    float*  m1   = (float*)alloc((size_t)SIGx*HIDx*4);
    float*  d1   = (float*)alloc((size_t)SIGx*HIDx*4);
    float*  m2   = (float*)alloc((size_t)SIGx*HIDx*4);
    float*  d2   = (float*)alloc((size_t)SIGx*HIDx*4);
    float*  sig  = (float*)alloc((size_t)Bx*SIGx*4);
    size_t fixed = off;

    // chunk buffers: adj fp8 (c*512*512) + h2q + s1q/s2q (c*256*512 each)
    int BC = 1;
    for (int c = Bx; c >= 1; c >>= 1) {
        size_t need = fixed + alignup((size_t)c*Nx*Nx)
                            + 2*alignup((size_t)c*HIDx*Nx);
        if (need <= ws_size) { BC = c; break; }
    }
    uchar* Padj = (uchar*)alloc((size_t)BC*Nx*Nx);       // adj fp8
    uchar* P1   = (uchar*)alloc((size_t)BC*HIDx*Nx);     // h2q
    uchar* P2   = (uchar*)alloc((size_t)BC*HIDx*Nx);     // s1q / s2q

    hipLaunchKernelGGL(kA_sample, dim3(Bx), dim3(Nx), 0, stream, x, z, mg, feat, flp);
    hipLaunchKernelGGL(kPrep, dim3(512), dim3(256), 0, stream, c1, c2, w2, c1q, c2q, w2tq);

    const int nch = Bx / BC;
    for (int c = 0; c < nch; ++c) {
        int b0 = c * BC;
        const float* featL = feat + (size_t)b0*Nx*3;
        ushort* t1L = t1 + (size_t)b0*SIGx*HIDx;
        ushort* t2L = t2 + (size_t)b0*SIGx*HIDx;
        // adj (fp8) + rank-3 pass-1 -> s1q
        hipLaunchKernelGGL(kFuse1, dim3(BC), dim3(512), 0, stream,
                           featL, w1, b1, Padj, P2);
        // t1 = (1/16) * c1q @ s1q   -> bf16
        hipLaunchKernelGGL((kGstdQ<512,256,false,false>), dim3(4, BC), dim3(256), 0, stream,
                           c1q, P2, (void*)t1L, 0.0625f);
        // h2q = (1/16) * w2tq @ s1q^T-staged -> fp8
        hipLaunchKernelGGL((kGstdQ<256,512,true,true>), dim3(8, BC), dim3(256), 0, stream,
                           w2tq, P2, (void*)P1, 0.0625f);
        // s2q = 0.25 * relu(h2q @ adj + b2) -> fp8
        hipLaunchKernelGGL(kGemmAdjQ, dim3(8, BC), dim3(256), 0, stream, P1, Padj, b2, P2);
        // t2 = 0.25 * c2q @ s2q  (16 * 1/4 undone) -> bf16
        hipLaunchKernelGGL((kGstdQ<512,256,false,false>), dim3(4, BC), dim3(256), 0, stream,
                           c2q, P2, (void*)t2L, 0.25f);
    }

    hipLaunchKernelGGL(kF1_stats, dim3(SIGx), dim3(1024), 0, stream,
                       t1, t2, m1, d1, m2, d2);
    hipLaunchKernelGGL(kF2_sig, dim3(SIGx, Bx), dim3(256), 0, stream,
                       (const __hip_bfloat16*)t1, (const __hip_bfloat16*)t2, m1, d1, m2, d2, sig);
    hipLaunchKernelGGL(kG_out, dim3(Bx), dim3(256), 0, stream, sig, fw, fbv, out);
}

// Round 9
// 316.596 us; speedup vs baseline: 1.6619x; 1.1359x over previous
//
#include <hip/hip_runtime.h>
#include <hip/hip_bf16.h>
#include <math.h>

#define Bx   256
#define Nx   512
#define SIGx 256
#define HIDx 256
#define OUTx 10
#define Hx   256

typedef __attribute__((ext_vector_type(4))) float f32x4;
typedef long fp8x8;          // 8 fp8 bytes = 2 VGPRs (MFMA A/B operand)
typedef unsigned char uchar;

__device__ inline uchar f2fp8(float v) {
    int r = __builtin_amdgcn_cvt_pk_fp8_f32(v, 0.0f, 0, false);
    return (uchar)(r & 0xff);
}
__device__ inline uint pk4fp8(float a0, float a1, float a2, float a3) {
    int r = __builtin_amdgcn_cvt_pk_fp8_f32(a0, a1, 0, false);
    r = __builtin_amdgcn_cvt_pk_fp8_f32(a2, a3, r, true);
    return (uint)r;
}

// ---------------------------------------------------------------------------
// Kernel A: sampling stage (mixture fields constant over m => unif dead).
// ---------------------------------------------------------------------------
__global__ __launch_bounds__(512) void kA_sample(
    const float* __restrict__ x, const float* __restrict__ z,
    const float* __restrict__ mg, float* __restrict__ feat,
    float* __restrict__ flp)
{
    int b = blockIdx.x;
    int n = threadIdx.x;
    int g = n >> 5;
    float mux = mg[g*6+1];
    float muy = mg[g*6+2];
    float sxv = expf(mg[g*6+3]);
    float syv = expf(mg[g*6+4]);
    float rho = tanhf(mg[g*6+5]);
    float z1 = z[((size_t)b*Nx + n)*2 + 0];
    float z2 = z[((size_t)b*Nx + n)*2 + 1];
    float omr2 = 1.0f - rho*rho;
    float xs = mux + sxv*z1;
    float ys = muy + syv*(rho*z1 + sqrtf(omr2)*z2);
    float dx = xs - mux, dy = ys - muy;
    float quad = (dx*dx/(sxv*sxv) - 2.0f*rho*dx*dy/(sxv*syv) + dy*dy/(syv*syv)) / omr2;
    float logprob = -1.8378770664093453f - logf(sxv*syv) - 0.5f*logf(omr2) - 0.5f*quad;
    float lx = tanhf(xs), ly = tanhf(ys);
    int px = (int)truncf(0.5f*(lx+1.0f)*(float)Hx - 0.1f);
    int py = (int)truncf(0.5f*(ly+1.0f)*(float)Hx - 0.1f);
    px = px < 0 ? 0 : (px > Hx-1 ? Hx-1 : px);
    py = py < 0 ? 0 : (py > Hx-1 ? Hx-1 : py);
    float pv = x[(size_t)b*Hx*Hx + (size_t)px*Hx + py];
    size_t fo = ((size_t)b*Nx + n)*3;
    feat[fo+0] = pv; feat[fo+1] = lx; feat[fo+2] = ly;

    __shared__ float red[512];
    red[n] = logprob;
    __syncthreads();
    for (int st = 256; st > 0; st >>= 1) {
        if (n < st) red[n] += red[n+st];
        __syncthreads();
    }
    if (n == 0) flp[b] = red[0];
}

// ---------------------------------------------------------------------------
// Prep: c1,c2 -> fp8 (x16 scale); w2 -> w2t fp8 (x16, transposed).
// ---------------------------------------------------------------------------
__global__ __launch_bounds__(256) void kPrep(
    const float* __restrict__ c1, const float* __restrict__ c2,
    const float* __restrict__ w2,
    uchar* __restrict__ c1q, uchar* __restrict__ c2q, uchar* __restrict__ w2tq)
{
    int idx = blockIdx.x*256 + threadIdx.x;
    if (idx < SIGx*Nx) {
        c1q[idx] = f2fp8(16.0f * c1[idx]);
        c2q[idx] = f2fp8(16.0f * c2[idx]);
    }
    if (idx < HIDx*HIDx) {
        int i = idx >> 8, j = idx & 255;
        w2tq[idx] = f2fp8(16.0f * w2[j*HIDx + i]);
    }
}

// ===========================================================================
// kFuse1: per b -- generate adj (fp8, materialized), accumulate
// G[c][n] = sum_m featT[c][m]*adj[m][n] fp32, rank-3 epilogue
// s1t[h][n] = relu(w1[.][h].G + b1[h]) -> fp8.
// 512 thr: tq = t&127 owns 4 consecutive n (uchar4 stores, 256B/wave);
// mc = t>>7 splits the m-sum in 4 chunks; G reduced via LDS.
// ===========================================================================
__global__ __launch_bounds__(512) void kFuse1(
    const float* __restrict__ featL, const float* __restrict__ w1,
    const float* __restrict__ b1,
    uchar* __restrict__ adjAll, uchar* __restrict__ s1tAll)
{
    int b = blockIdx.x;
    const float* fb = featL + (size_t)b*Nx*3;
    uchar* adj = adjAll + (size_t)b*Nx*Nx;
    uchar* s1t = s1tAll + (size_t)b*HIDx*Nx;

    __shared__ float fpv[Nx], flx[Nx], fly[Nx], fH[Nx];
    __shared__ float w1s[3*HIDx], b1s[HIDx];
    __shared__ float Gp[4][3][Nx];

    int t = threadIdx.x;
    {
        float pv = fb[t*3+0], lx = fb[t*3+1], ly = fb[t*3+2];
        fpv[t] = pv; flx[t] = lx; fly[t] = ly;
        fH[t] = fmaf(0.5f*lx, lx, fmaf(0.5f*ly, ly, 1.0f));
    }
    for (int i = t; i < 3*HIDx; i += 512) w1s[i] = w1[i];
    if (t < HIDx) b1s[t] = b1[t];
    __syncthreads();

    int tq = t & 127;          // column-quad index: n = 4*tq .. 4*tq+3
    int mc = t >> 7;           // m-chunk 0..3 (128 m each)
    int n4 = tq*4;

    float xn[4], yn[4], cn[4];
    #pragma unroll
    for (int e = 0; e < 4; ++e) {
        xn[e] = flx[n4+e]; yn[e] = fly[n4+e];
        cn[e] = fmaf(0.5f*xn[e], xn[e], 0.5f*yn[e]*yn[e]);
    }
    float G0[4] = {}, G1[4] = {}, G2[4] = {};

    int m0 = mc*128;
    #pragma unroll 4
    for (int mm = 0; mm < 128; ++mm) {
        int m = m0 + mm;
        float hx = fH[m], fx = flx[m], fy = fly[m];
        float a[4];
        #pragma unroll
        for (int e = 0; e < 4; ++e) {
            float s = fmaf(-yn[e], fy, fmaf(-xn[e], fx, hx + cn[e]));
            a[e] = __builtin_amdgcn_rcpf(s);
            G0[e] = fmaf(a[e], fpv[m], G0[e]);
            G1[e] = fmaf(a[e], fx, G1[e]);
            G2[e] = fmaf(a[e], fy, G2[e]);
        }
        *(uint*)(adj + (size_t)m*Nx + n4) = pk4fp8(a[0], a[1], a[2], a[3]);
    }

    *(f32x4*)&Gp[mc][0][n4] = (f32x4){G0[0],G0[1],G0[2],G0[3]};
    *(f32x4*)&Gp[mc][1][n4] = (f32x4){G1[0],G1[1],G1[2],G1[3]};
    *(f32x4*)&Gp[mc][2][n4] = (f32x4){G2[0],G2[1],G2[2],G2[3]};
    __syncthreads();

    // totals for my 4 columns
    f32x4 T0 = {}, T1 = {}, T2 = {};
    #pragma unroll
    for (int j = 0; j < 4; ++j) {
        T0 += *(const f32x4*)&Gp[j][0][n4];
        T1 += *(const f32x4*)&Gp[j][1][n4];
        T2 += *(const f32x4*)&Gp[j][2][n4];
    }

    int hc = mc;               // reuse the t>>7 split for 4 h-chunks of 64
    #pragma unroll 4
    for (int hh = 0; hh < 64; ++hh) {
        int h = hc*64 + hh;
        float w0 = w1s[h], wA = w1s[HIDx+h], wB = w1s[2*HIDx+h], bb = b1s[h];
        float v0 = fminf(fmaxf(fmaf(T0.x,w0, fmaf(T1.x,wA, fmaf(T2.x,wB, bb))), 0.0f), 448.0f);
        float v1 = fminf(fmaxf(fmaf(T0.y,w0, fmaf(T1.y,wA, fmaf(T2.y,wB, bb))), 0.0f), 448.0f);
        float v2 = fminf(fmaxf(fmaf(T0.z,w0, fmaf(T1.z,wA, fmaf(T2.z,wB, bb))), 0.0f), 448.0f);
        float v3 = fminf(fmaxf(fmaf(T0.w,w0, fmaf(T1.w,wA, fmaf(T2.w,wB, bb))), 0.0f), 448.0f);
        *(uint*)(s1t + (size_t)h*Nx + n4) = pk4fp8(v0, v1, v2, v3);
    }
}

// ===========================================================================
// kGemmAdjQ (pass 2): s2t[h][n] = 0.25*relu(sum_m h2t[h][m]*adj[m][n]+b2[h]).
// Grid (BC, 8): b = blockIdx.x -> all 8 tiles of b share an XCD (L2 reuse).
// ===========================================================================
__global__ __launch_bounds__(256) void kGemmAdjQ(
    const uchar* __restrict__ Aall, const uchar* __restrict__ adjAll,
    const float* __restrict__ bias, uchar* __restrict__ outAll)
{
    int b    = blockIdx.x;
    int tile = blockIdx.y;
    int rt = tile >> 2;
    int ct = tile & 3;
    const uchar* A = Aall + (size_t)b*HIDx*Nx;
    const uchar* Badj = adjAll + (size_t)b*Nx*Nx;
    uchar* outp = outAll + (size_t)b*HIDx*Nx;

    __shared__ uchar Als[128][80];
    __shared__ uchar Bls[128][80];
    int t = threadIdx.x;
    int lane = t & 63, wave = t >> 6;
    int wr = wave >> 1, wc = wave & 1;
    int q = lane >> 4, c16 = lane & 15;
    int r0 = rt*128, n0 = ct*128;
    f32x4 acc[4][4] = {};

    for (int kk = 0; kk < Nx; kk += 64) {
        #pragma unroll
        for (int cc = 0; cc < 2; ++cc) {
            int c = t + cc*256;
            int row = c >> 2;
            int ko = (c & 3) * 16;
            *(float4*)&Als[row][ko] = *(const float4*)(A + (size_t)(r0+row)*Nx + kk + ko);
            *(float4*)&Bls[row][ko] = *(const float4*)(Badj + (size_t)(n0+row)*Nx + kk + ko);
        }
        __syncthreads();
        #pragma unroll
        for (int ks = 0; ks < 64; ks += 32) {
            fp8x8 af[4], bfr[4];
            #pragma unroll
            for (int i = 0; i < 4; ++i)
                af[i] = *(const fp8x8*)&Als[wr*64 + i*16 + c16][ks + q*8];
            #pragma unroll
            for (int j = 0; j < 4; ++j)
                bfr[j] = *(const fp8x8*)&Bls[wc*64 + j*16 + c16][ks + q*8];
            #pragma unroll
            for (int i = 0; i < 4; ++i)
                #pragma unroll
                for (int j = 0; j < 4; ++j)
                    acc[i][j] = __builtin_amdgcn_mfma_f32_16x16x32_fp8_fp8(af[i], bfr[j], acc[i][j], 0, 0, 0);
        }
        __syncthreads();
    }
    #pragma unroll
    for (int i = 0; i < 4; ++i) {
        int rowb = r0 + wr*64 + i*16 + q*4;
        #pragma unroll
        for (int j = 0; j < 4; ++j) {
            int col = n0 + wc*64 + j*16 + c16;
            #pragma unroll
            for (int r = 0; r < 4; ++r) {
                float v = fmaxf(acc[i][j][r] + bias[rowb + r], 0.0f) * 0.25f;
                outp[(size_t)(rowb + r)*Nx + col] = f2fp8(fminf(v, 448.0f));
            }
        }
    }
}

// ---------------------------------------------------------------------------
// kGstdQ: C[row][col] = oscale * sum_k A[row][k]*B[k][col], fp8 in, fp8 out.
// Grid (BC, tiles): b-major for XCD L2 locality.
// ---------------------------------------------------------------------------
template<int K, int NC, bool TRB>
__global__ __launch_bounds__(256) void kGstdQ(
    const uchar* __restrict__ Ash, const uchar* __restrict__ Ball,
    uchar* __restrict__ outAll, float oscale)
{
    constexpr int CT = NC / 128;
    int b    = blockIdx.x;
    int tile = blockIdx.y;
    int rt = tile / CT;
    int ct = tile % CT;
    const uchar* B = Ball + (size_t)b*HIDx*Nx;
    uchar* outp = outAll + (size_t)b*HIDx*NC;

    __shared__ uchar Als[128][80];
    __shared__ uchar Bls[128][80];
    int t = threadIdx.x;
    int lane = t & 63, wave = t >> 6;
    int wr = wave >> 1, wc = wave & 1;
    int q = lane >> 4, c16 = lane & 15;
    int r0 = rt*128, n0 = ct*128;
    f32x4 acc[4][4] = {};

    for (int kk = 0; kk < K; kk += 64) {
        #pragma unroll
        for (int cc = 0; cc < 2; ++cc) {
            int c = t + cc*256;
            int row = c >> 2;
            int ko = (c & 3) * 16;
            *(float4*)&Als[row][ko] = *(const float4*)(Ash + (size_t)(r0+row)*K + kk + ko);
        }
        if (!TRB) {
            #pragma unroll
            for (int cc = 0; cc < 2; ++cc) {
                int c = t + cc*256;
                int row = c >> 2;
                int ko = (c & 3) * 16;
                *(float4*)&Bls[row][ko] = *(const float4*)(B + (size_t)(n0+row)*K + kk + ko);
            }
        } else {
            int pi  = t & 31;          // k-pair within 64-k tile
            int nc8 = t >> 5;          // 8 col-groups of 16
            int hk = kk + 2*pi;
            const uchar* g0 = B + (size_t)hk*NC + n0 + nc8*16;
            const uchar* g1 = g0 + NC;
            float4 v0 = *(const float4*)g0;
            float4 v1 = *(const float4*)g1;
            const uchar* pa = (const uchar*)&v0;
            const uchar* qa = (const uchar*)&v1;
            #pragma unroll
            for (int e = 0; e < 16; ++e)
                *(ushort*)&Bls[nc8*16 + e][2*pi] = (ushort)pa[e] | ((ushort)qa[e] << 8);
        }
        __syncthreads();
        #pragma unroll
        for (int ks = 0; ks < 64; ks += 32) {
            fp8x8 af[4], bfr[4];
            #pragma unroll
            for (int i = 0; i < 4; ++i)
                af[i] = *(const fp8x8*)&Als[wr*64 + i*16 + c16][ks + q*8];
            #pragma unroll
            for (int j = 0; j < 4; ++j)
                bfr[j] = *(const fp8x8*)&Bls[wc*64 + j*16 + c16][ks + q*8];
            #pragma unroll
            for (int i = 0; i < 4; ++i)
                #pragma unroll
                for (int j = 0; j < 4; ++j)
                    acc[i][j] = __builtin_amdgcn_mfma_f32_16x16x32_fp8_fp8(af[i], bfr[j], acc[i][j], 0, 0, 0);
        }
        __syncthreads();
    }
    #pragma unroll
    for (int i = 0; i < 4; ++i) {
        int rowb = r0 + wr*64 + i*16 + q*4;
        #pragma unroll
        for (int j = 0; j < 4; ++j) {
            int col = n0 + wc*64 + j*16 + c16;
            #pragma unroll
            for (int r = 0; r < 4; ++r) {
                float v = acc[i][j][r] * oscale;
                v = fminf(fmaxf(v, -448.0f), 448.0f);
                outp[(size_t)(rowb + r)*NC + col] = f2fp8(v);
            }
        }
    }
}

// ---------------------------------------------------------------------------
// F1: single-pass online softmax-over-b stats for fp8 t1,t2. m and 1/d out.
// 512 thr = 64 h-quads x 8 b-groups of 32.
// ---------------------------------------------------------------------------
__global__ __launch_bounds__(512) void kF1q(
    const uchar* __restrict__ t1, const uchar* __restrict__ t2,
    float* __restrict__ m1, float* __restrict__ rd1,
    float* __restrict__ m2, float* __restrict__ rd2)
{
    int s = blockIdx.x;
    int t = threadIdx.x;
    int hq = t & 63;
    int bq = t >> 6;
    const size_t str = (size_t)SIGx*HIDx;
    size_t base = (size_t)(bq*32)*str + (size_t)s*HIDx + hq*4;

    float mv1[4], dv1[4], mv2[4], dv2[4];
    #pragma unroll
    for (int e = 0; e < 4; ++e) { mv1[e]=-3.0e38f; dv1[e]=0.0f; mv2[e]=-3.0e38f; dv2[e]=0.0f; }

    for (int i = 0; i < 32; ++i) {
        uint u1 = *(const uint*)(t1 + base + (size_t)i*str);
        uint u2 = *(const uint*)(t2 + base + (size_t)i*str);
        float v1[4], v2[4];
        v1[0] = __builtin_amdgcn_cvt_f32_fp8(u1, 0);
        v1[1] = __builtin_amdgcn_cvt_f32_fp8(u1, 1);
        v1[2] = __builtin_amdgcn_cvt_f32_fp8(u1, 2);
        v1[3] = __builtin_amdgcn_cvt_f32_fp8(u1, 3);
        v2[0] = __builtin_amdgcn_cvt_f32_fp8(u2, 0);
        v2[1] = __builtin_amdgcn_cvt_f32_fp8(u2, 1);
        v2[2] = __builtin_amdgcn_cvt_f32_fp8(u2, 2);
        v2[3] = __builtin_amdgcn_cvt_f32_fp8(u2, 3);
        #pragma unroll
        for (int e = 0; e < 4; ++e) {
            float mn;
            mn = fmaxf(mv1[e], v1[e]);
            dv1[e] = dv1[e]*__expf(mv1[e]-mn) + __expf(v1[e]-mn); mv1[e] = mn;
            mn = fmaxf(mv2[e], v2[e]);
            dv2[e] = dv2[e]*__expf(mv2[e]-mn) + __expf(v2[e]-mn); mv2[e] = mn;
        }
    }

    __shared__ float pm1[8][256], pd1[8][256], pm2[8][256], pd2[8][256];
    #pragma unroll
    for (int e = 0; e < 4; ++e) {
        pm1[bq][hq*4+e] = mv1[e]; pd1[bq][hq*4+e] = dv1[e];
        pm2[bq][hq*4+e] = mv2[e]; pd2[bq][hq*4+e] = dv2[e];
    }
    __syncthreads();

    if (t < 256) {
        int h = t;
        float m = -3.0e38f, d = 0.0f;
        #pragma unroll
        for (int j = 0; j < 8; ++j) {
            float mm = pm1[j][h], dd = pd1[j][h];
            float mn = fmaxf(m, mm);
            d = d*__expf(m-mn) + dd*__expf(mm-mn);
            m = mn;
        }
        size_t o = (size_t)s*HIDx + h;
        m1[o] = m; rd1[o] = 1.0f/d;
    } else {
        int h = t - 256;
        float m = -3.0e38f, d = 0.0f;
        #pragma unroll
        for (int j = 0; j < 8; ++j) {
            float mm = pm2[j][h], dd = pd2[j][h];
            float mn = fmaxf(m, mm);
            d = d*__expf(m-mn) + dd*__expf(mm-mn);
            m = mn;
        }
        size_t o = (size_t)s*HIDx + h;
        m2[o] = m; rd2[o] = 1.0f/d;
    }
}

// ---------------------------------------------------------------------------
// F2: sig[b,s] = sum_h exp(t1-m1)*rd1 + exp(t2-m2)*rd2 (fp8 t).
// Block 256 thr handles 4 s for one b (wave per s).
// ---------------------------------------------------------------------------
__global__ __launch_bounds__(256) void kF2q(
    const uchar* __restrict__ t1, const uchar* __restrict__ t2,
    const float* __restrict__ m1, const float* __restrict__ rd1,
    const float* __restrict__ m2, const float* __restrict__ rd2,
    float* __restrict__ sig)
{
    int b = blockIdx.y;
    int sq = threadIdx.x >> 6;
    int s = blockIdx.x*4 + sq;
    int hq = threadIdx.x & 63;
    size_t sh = (size_t)s*HIDx + hq*4;
    size_t tb = ((size_t)b*SIGx + s)*HIDx + hq*4;
    uint u1 = *(const uint*)(t1 + tb);
    uint u2 = *(const uint*)(t2 + tb);
    f32x4 a1 = *(const f32x4*)&m1[sh];
    f32x4 r1 = *(const f32x4*)&rd1[sh];
    f32x4 a2 = *(const f32x4*)&m2[sh];
    f32x4 r2 = *(const f32x4*)&rd2[sh];
    float v = 0.0f;
    v += __expf(__builtin_amdgcn_cvt_f32_fp8(u1,0) - a1.x) * r1.x;
    v += __expf(__builtin_amdgcn_cvt_f32_fp8(u1,1) - a1.y) * r1.y;
    v += __expf(__builtin_amdgcn_cvt_f32_fp8(u1,2) - a1.z) * r1.z;
    v += __expf(__builtin_amdgcn_cvt_f32_fp8(u1,3) - a1.w) * r1.w;
    v += __expf(__builtin_amdgcn_cvt_f32_fp8(u2,0) - a2.x) * r2.x;
    v += __expf(__builtin_amdgcn_cvt_f32_fp8(u2,1) - a2.y) * r2.y;
    v += __expf(__builtin_amdgcn_cvt_f32_fp8(u2,2) - a2.z) * r2.z;
    v += __expf(__builtin_amdgcn_cvt_f32_fp8(u2,3) - a2.w) * r2.w;

    __shared__ float red[256];
    red[threadIdx.x] = v;
    __syncthreads();
    for (int st = 32; st > 0; st >>= 1) {
        if (hq < st) red[threadIdx.x] += red[threadIdx.x + st];
        __syncthreads();
    }
    if (hq == 0) sig[(size_t)b*SIGx + s] = red[sq*64];
}

// ---------------------------------------------------------------------------
// G: out[b,:] = softmax(sig[b,:] @ fcf_w.T + fcf_b)
// ---------------------------------------------------------------------------
__global__ __launch_bounds__(256) void kG_out(
    const float* __restrict__ sig, const float* __restrict__ fw,
    const float* __restrict__ fb, float* __restrict__ out)
{
    int b = blockIdx.x;
    int tid = threadIdx.x;
    __shared__ float red[256];
    __shared__ float logits[OUTx];
    float sv = sig[(size_t)b*SIGx + tid];
    for (int o = 0; o < OUTx; ++o) {
        red[tid] = sv * fw[o*SIGx + tid];
        __syncthreads();
        for (int st = 128; st > 0; st >>= 1) {
            if (tid < st) red[tid] += red[tid+st];
            __syncthreads();
        }
        if (tid == 0) logits[o] = red[0] + fb[o];
        __syncthreads();
    }
    if (tid == 0) {
        float mx = logits[0];
        for (int o = 1; o < OUTx; ++o) mx = fmaxf(mx, logits[o]);
        float dd = 0.0f; float e[OUTx];
        for (int o = 0; o < OUTx; ++o) { e[o] = expf(logits[o]-mx); dd += e[o]; }
        float inv = 1.0f/dd;
        for (int o = 0; o < OUTx; ++o) out[(size_t)b*OUTx + o] = e[o]*inv;
    }
}

// ---------------------------------------------------------------------------
static inline size_t alignup(size_t b) { return (b + 255) & ~(size_t)255; }

extern "C" void kernel_launch(void* const* d_in, const int* in_sizes, int n_in,
                              void* d_out, int out_size, void* d_ws, size_t ws_size,
                              hipStream_t stream)
{
    const float* x   = (const float*)d_in[0];
    // d_in[1] = unif -- dead
    const float* z   = (const float*)d_in[2];
    const float* mg  = (const float*)d_in[3];
    const float* w1  = (const float*)d_in[4];
    const float* b1  = (const float*)d_in[5];
    const float* w2  = (const float*)d_in[6];
    const float* b2  = (const float*)d_in[7];
    const float* c1  = (const float*)d_in[8];
    const float* c2  = (const float*)d_in[9];
    const float* fw  = (const float*)d_in[10];
    const float* fbv = (const float*)d_in[11];
    float* out = (float*)d_out;
    float* flp = out + (size_t)Bx*OUTx;
    (void)in_sizes; (void)n_in; (void)out_size;

    char* ws = (char*)d_ws;
    size_t off = 0;
    auto alloc = [&](size_t bytes) -> char* {
        char* p = ws + off; off += alignup(bytes); return p;
    };
    float*  feat = (float*)alloc((size_t)Bx*Nx*3*4);
    uchar*  c1q  = (uchar*)alloc((size_t)SIGx*Nx);
    uchar*  c2q  = (uchar*)alloc((size_t)SIGx*Nx);
    uchar*  w2tq = (uchar*)alloc((size_t)HIDx*HIDx);
    uchar*  t1   = (uchar*)alloc((size_t)Bx*SIGx*HIDx);   // fp8 t
    uchar*  t2   = (uchar*)alloc((size_t)Bx*SIGx*HIDx);
    float*  m1   = (float*)alloc((size_t)SIGx*HIDx*4);
    float*  d1   = (float*)alloc((size_t)SIGx*HIDx*4);
    float*  m2   = (float*)alloc((size_t)SIGx*HIDx*4);
    float*  d2   = (float*)alloc((size_t)SIGx*HIDx*4);
    float*  sig  = (float*)alloc((size_t)Bx*SIGx*4);
    size_t fixed = off;

    // chunk buffers: adj fp8 (c*512*512) + h2q + s1q/s2q (c*256*512 each)
    int BC = 1;
    for (int c = Bx; c >= 1; c >>= 1) {
        size_t need = fixed + alignup((size_t)c*Nx*Nx)
                            + 2*alignup((size_t)c*HIDx*Nx);
        if (need <= ws_size) { BC = c; break; }
    }
    uchar* Padj = (uchar*)alloc((size_t)BC*Nx*Nx);       // adj fp8
    uchar* P1   = (uchar*)alloc((size_t)BC*HIDx*Nx);     // h2q
    uchar* P2   = (uchar*)alloc((size_t)BC*HIDx*Nx);     // s1q / s2q

    hipLaunchKernelGGL(kA_sample, dim3(Bx), dim3(Nx), 0, stream, x, z, mg, feat, flp);
    hipLaunchKernelGGL(kPrep, dim3(512), dim3(256), 0, stream, c1, c2, w2, c1q, c2q, w2tq);

    const int nch = Bx / BC;
    for (int c = 0; c < nch; ++c) {
        int b0 = c * BC;
        const float* featL = feat + (size_t)b0*Nx*3;
        uchar* t1L = t1 + (size_t)b0*SIGx*HIDx;
        uchar* t2L = t2 + (size_t)b0*SIGx*HIDx;
        // adj (fp8) + rank-3 pass-1 -> s1q
        hipLaunchKernelGGL(kFuse1, dim3(BC), dim3(512), 0, stream,
                           featL, w1, b1, Padj, P2);
        // t1 = (1/16) * c1q @ s1q -> fp8
        hipLaunchKernelGGL((kGstdQ<512,256,false>), dim3(BC, 4), dim3(256), 0, stream,
                           c1q, P2, t1L, 0.0625f);
        // h2q = (1/16) * w2tq @ s1q^T-staged -> fp8
        hipLaunchKernelGGL((kGstdQ<256,512,true>), dim3(BC, 8), dim3(256), 0, stream,
                           w2tq, P2, P1, 0.0625f);
        // s2q = 0.25 * relu(h2q @ adj + b2) -> fp8
        hipLaunchKernelGGL(kGemmAdjQ, dim3(BC, 8), dim3(256), 0, stream, P1, Padj, b2, P2);
        // t2 = 0.25 * c2q @ s2q  (16 * 1/4 undone) -> fp8
        hipLaunchKernelGGL((kGstdQ<512,256,false>), dim3(BC, 4), dim3(256), 0, stream,
                           c2q, P2, t2L, 0.25f);
    }

    hipLaunchKernelGGL(kF1q, dim3(SIGx), dim3(512), 0, stream,
                       t1, t2, m1, d1, m2, d2);
    hipLaunchKernelGGL(kF2q, dim3(SIGx/4, Bx), dim3(256), 0, stream,
                       t1, t2, m1, d1, m2, d2, sig);
    hipLaunchKernelGGL(kG_out, dim3(Bx), dim3(256), 0, stream, sig, fw, fbv, out);
}

// Round 10
// 291.409 us; speedup vs baseline: 1.8056x; 1.0864x over previous
//
#include <hip/hip_runtime.h>
#include <hip/hip_bf16.h>
#include <math.h>

#define Bx   256
#define Nx   512
#define SIGx 256
#define HIDx 256
#define OUTx 10
#define Hx   256

typedef __attribute__((ext_vector_type(4))) float f32x4;
typedef long fp8x8;          // 8 fp8 bytes = 2 VGPRs (MFMA A/B operand)
typedef unsigned char uchar;

__device__ inline uchar f2fp8(float v) {
    int r = __builtin_amdgcn_cvt_pk_fp8_f32(v, 0.0f, 0, false);
    return (uchar)(r & 0xff);
}
__device__ inline uint pk4fp8(float a0, float a1, float a2, float a3) {
    int r = __builtin_amdgcn_cvt_pk_fp8_f32(a0, a1, 0, false);
    r = __builtin_amdgcn_cvt_pk_fp8_f32(a2, a3, r, true);
    return (uint)r;
}

// async global->LDS, 16B per lane; lds dest = wave-uniform base + lane*16
__device__ inline void gload_lds16(const uchar* g, uchar* l) {
    __builtin_amdgcn_global_load_lds(
        (const __attribute__((address_space(1))) uint*)g,
        (__attribute__((address_space(3))) uint*)l, 16, 0, 0);
}
// swizzled LDS fragment address: 64B rows, 16B-unit XOR swizzle
__device__ inline const uchar* laddr(const uchar* base, int row, int kb) {
    int ps = (kb >> 4) ^ ((row >> 1) & 3) ^ ((row >> 4) & 3);
    return base + row*64 + ps*16 + (kb & 15);
}

// ---------------------------------------------------------------------------
// Kernel A: sampling stage (mixture fields constant over m => unif dead).
// ---------------------------------------------------------------------------
__global__ __launch_bounds__(512) void kA_sample(
    const float* __restrict__ x, const float* __restrict__ z,
    const float* __restrict__ mg, float* __restrict__ feat,
    float* __restrict__ flp)
{
    int b = blockIdx.x;
    int n = threadIdx.x;
    int g = n >> 5;
    float mux = mg[g*6+1];
    float muy = mg[g*6+2];
    float sxv = expf(mg[g*6+3]);
    float syv = expf(mg[g*6+4]);
    float rho = tanhf(mg[g*6+5]);
    float z1 = z[((size_t)b*Nx + n)*2 + 0];
    float z2 = z[((size_t)b*Nx + n)*2 + 1];
    float omr2 = 1.0f - rho*rho;
    float xs = mux + sxv*z1;
    float ys = muy + syv*(rho*z1 + sqrtf(omr2)*z2);
    float dx = xs - mux, dy = ys - muy;
    float quad = (dx*dx/(sxv*sxv) - 2.0f*rho*dx*dy/(sxv*syv) + dy*dy/(syv*syv)) / omr2;
    float logprob = -1.8378770664093453f - logf(sxv*syv) - 0.5f*logf(omr2) - 0.5f*quad;
    float lx = tanhf(xs), ly = tanhf(ys);
    int px = (int)truncf(0.5f*(lx+1.0f)*(float)Hx - 0.1f);
    int py = (int)truncf(0.5f*(ly+1.0f)*(float)Hx - 0.1f);
    px = px < 0 ? 0 : (px > Hx-1 ? Hx-1 : px);
    py = py < 0 ? 0 : (py > Hx-1 ? Hx-1 : py);
    float pv = x[(size_t)b*Hx*Hx + (size_t)px*Hx + py];
    size_t fo = ((size_t)b*Nx + n)*3;
    feat[fo+0] = pv; feat[fo+1] = lx; feat[fo+2] = ly;

    __shared__ float red[512];
    red[n] = logprob;
    __syncthreads();
    for (int st = 256; st > 0; st >>= 1) {
        if (n < st) red[n] += red[n+st];
        __syncthreads();
    }
    if (n == 0) flp[b] = red[0];
}

// ---------------------------------------------------------------------------
// Prep: c1,c2 -> fp8 (x16 scale); w2 -> w2t fp8 (x16, transposed).
// ---------------------------------------------------------------------------
__global__ __launch_bounds__(256) void kPrep(
    const float* __restrict__ c1, const float* __restrict__ c2,
    const float* __restrict__ w2,
    uchar* __restrict__ c1q, uchar* __restrict__ c2q, uchar* __restrict__ w2tq)
{
    int idx = blockIdx.x*256 + threadIdx.x;
    if (idx < SIGx*Nx) {
        c1q[idx] = f2fp8(16.0f * c1[idx]);
        c2q[idx] = f2fp8(16.0f * c2[idx]);
    }
    if (idx < HIDx*HIDx) {
        int i = idx >> 8, j = idx & 255;
        w2tq[idx] = f2fp8(16.0f * w2[j*HIDx + i]);
    }
}

// ===========================================================================
// kFuse1: per b -- generate adj (fp8, materialized), accumulate
// G[c][n] = sum_m featT[c][m]*adj[m][n] fp32, rank-3 epilogue
// s1t[h][n] = relu(w1[.][h].G + b1[h]) -> fp8.
// ===========================================================================
__global__ __launch_bounds__(512) void kFuse1(
    const float* __restrict__ featL, const float* __restrict__ w1,
    const float* __restrict__ b1,
    uchar* __restrict__ adjAll, uchar* __restrict__ s1tAll)
{
    int b = blockIdx.x;
    const float* fb = featL + (size_t)b*Nx*3;
    uchar* adj = adjAll + (size_t)b*Nx*Nx;
    uchar* s1t = s1tAll + (size_t)b*HIDx*Nx;

    __shared__ float fpv[Nx], flx[Nx], fly[Nx], fH[Nx];
    __shared__ float w1s[3*HIDx], b1s[HIDx];
    __shared__ float Gp[4][3][Nx];

    int t = threadIdx.x;
    {
        float pv = fb[t*3+0], lx = fb[t*3+1], ly = fb[t*3+2];
        fpv[t] = pv; flx[t] = lx; fly[t] = ly;
        fH[t] = fmaf(0.5f*lx, lx, fmaf(0.5f*ly, ly, 1.0f));
    }
    for (int i = t; i < 3*HIDx; i += 512) w1s[i] = w1[i];
    if (t < HIDx) b1s[t] = b1[t];
    __syncthreads();

    int tq = t & 127;          // column-quad index: n = 4*tq .. 4*tq+3
    int mc = t >> 7;           // m-chunk 0..3 (128 m each)
    int n4 = tq*4;

    float xn[4], yn[4], cn[4];
    #pragma unroll
    for (int e = 0; e < 4; ++e) {
        xn[e] = flx[n4+e]; yn[e] = fly[n4+e];
        cn[e] = fmaf(0.5f*xn[e], xn[e], 0.5f*yn[e]*yn[e]);
    }
    float G0[4] = {}, G1[4] = {}, G2[4] = {};

    int m0 = mc*128;
    #pragma unroll 4
    for (int mm = 0; mm < 128; ++mm) {
        int m = m0 + mm;
        float hx = fH[m], fx = flx[m], fy = fly[m];
        float a[4];
        #pragma unroll
        for (int e = 0; e < 4; ++e) {
            float s = fmaf(-yn[e], fy, fmaf(-xn[e], fx, hx + cn[e]));
            a[e] = __builtin_amdgcn_rcpf(s);
            G0[e] = fmaf(a[e], fpv[m], G0[e]);
            G1[e] = fmaf(a[e], fx, G1[e]);
            G2[e] = fmaf(a[e], fy, G2[e]);
        }
        *(uint*)(adj + (size_t)m*Nx + n4) = pk4fp8(a[0], a[1], a[2], a[3]);
    }

    *(f32x4*)&Gp[mc][0][n4] = (f32x4){G0[0],G0[1],G0[2],G0[3]};
    *(f32x4*)&Gp[mc][1][n4] = (f32x4){G1[0],G1[1],G1[2],G1[3]};
    *(f32x4*)&Gp[mc][2][n4] = (f32x4){G2[0],G2[1],G2[2],G2[3]};
    __syncthreads();

    f32x4 T0 = {}, T1 = {}, T2 = {};
    #pragma unroll
    for (int j = 0; j < 4; ++j) {
        T0 += *(const f32x4*)&Gp[j][0][n4];
        T1 += *(const f32x4*)&Gp[j][1][n4];
        T2 += *(const f32x4*)&Gp[j][2][n4];
    }

    int hc = mc;
    #pragma unroll 4
    for (int hh = 0; hh < 64; ++hh) {
        int h = hc*64 + hh;
        float w0 = w1s[h], wA = w1s[HIDx+h], wB = w1s[2*HIDx+h], bb = b1s[h];
        float v0 = fminf(fmaxf(fmaf(T0.x,w0, fmaf(T1.x,wA, fmaf(T2.x,wB, bb))), 0.0f), 448.0f);
        float v1 = fminf(fmaxf(fmaf(T0.y,w0, fmaf(T1.y,wA, fmaf(T2.y,wB, bb))), 0.0f), 448.0f);
        float v2 = fminf(fmaxf(fmaf(T0.z,w0, fmaf(T1.z,wA, fmaf(T2.z,wB, bb))), 0.0f), 448.0f);
        float v3 = fminf(fmaxf(fmaf(T0.w,w0, fmaf(T1.w,wA, fmaf(T2.w,wB, bb))), 0.0f), 448.0f);
        *(uint*)(s1t + (size_t)h*Nx + n4) = pk4fp8(v0, v1, v2, v3);
    }
}

// ===========================================================================
// kGemmAdjQ (pass 2): s2t[h][n] = 0.25*relu(sum_m h2t[h][m]*adj[m][n]+b2[h]).
// Async global_load_lds staging into XOR-swizzled 64B-row tiles.
// Grid (BC, 8): b-major -> all tiles of b share an XCD (L2 reuse).
// ===========================================================================
__global__ __launch_bounds__(256) void kGemmAdjQ(
    const uchar* __restrict__ Aall, const uchar* __restrict__ adjAll,
    const float* __restrict__ bias, uchar* __restrict__ outAll)
{
    int b    = blockIdx.x;
    int tile = blockIdx.y;
    int rt = tile >> 2;
    int ct = tile & 3;
    const uchar* A = Aall + (size_t)b*HIDx*Nx;
    const uchar* Badj = adjAll + (size_t)b*Nx*Nx;
    uchar* outp = outAll + (size_t)b*HIDx*Nx;

    __shared__ __align__(16) uchar Als[128*64];
    __shared__ __align__(16) uchar Bls[128*64];
    int t = threadIdx.x;
    int lane = t & 63, wave = t >> 6;
    int wr = wave >> 1, wc = wave & 1;
    int q = lane >> 4, c16 = lane & 15;
    int r0 = rt*128, n0 = ct*128;
    int lrow = lane >> 2;      // row-within-chunk for staging
    int pu   = lane & 3;       // 16B-unit within row
    f32x4 acc[4][4] = {};

    for (int kk = 0; kk < Nx; kk += 64) {
        #pragma unroll
        for (int r = 0; r < 2; ++r) {
            int chunk = wave*2 + r;
            int row = chunk*16 + lrow;
            int sl = pu ^ ((row>>1)&3) ^ ((row>>4)&3);
            gload_lds16(A + (size_t)(r0+row)*Nx + kk + sl*16, Als + chunk*1024);
            gload_lds16(Badj + (size_t)(n0+row)*Nx + kk + sl*16, Bls + chunk*1024);
        }
        __syncthreads();
        #pragma unroll
        for (int ks = 0; ks < 64; ks += 32) {
            fp8x8 af[4], bfr[4];
            #pragma unroll
            for (int i = 0; i < 4; ++i)
                af[i] = *(const fp8x8*)laddr(Als, wr*64 + i*16 + c16, ks + q*8);
            #pragma unroll
            for (int j = 0; j < 4; ++j)
                bfr[j] = *(const fp8x8*)laddr(Bls, wc*64 + j*16 + c16, ks + q*8);
            #pragma unroll
            for (int i = 0; i < 4; ++i)
                #pragma unroll
                for (int j = 0; j < 4; ++j)
                    acc[i][j] = __builtin_amdgcn_mfma_f32_16x16x32_fp8_fp8(af[i], bfr[j], acc[i][j], 0, 0, 0);
        }
        __syncthreads();
    }
    #pragma unroll
    for (int i = 0; i < 4; ++i) {
        int rowb = r0 + wr*64 + i*16 + q*4;
        #pragma unroll
        for (int j = 0; j < 4; ++j) {
            int col = n0 + wc*64 + j*16 + c16;
            #pragma unroll
            for (int r = 0; r < 4; ++r) {
                float v = fmaxf(acc[i][j][r] + bias[rowb + r], 0.0f) * 0.25f;
                outp[(size_t)(rowb + r)*Nx + col] = f2fp8(fminf(v, 448.0f));
            }
        }
    }
}

// ---------------------------------------------------------------------------
// kGstdQ: C[row][col] = oscale * sum_k A[row][k]*B[k][col], fp8 in/out.
// A async-staged (swizzled). B: non-TRB async; TRB = VGPR transpose staging
// into the same swizzled layout. Grid (BC, tiles) b-major.
// ---------------------------------------------------------------------------
template<int K, int NC, bool TRB>
__global__ __launch_bounds__(256) void kGstdQ(
    const uchar* __restrict__ Ash, const uchar* __restrict__ Ball,
    uchar* __restrict__ outAll, float oscale)
{
    constexpr int CT = NC / 128;
    int b    = blockIdx.x;
    int tile = blockIdx.y;
    int rt = tile / CT;
    int ct = tile % CT;
    const uchar* B = Ball + (size_t)b*HIDx*Nx;
    uchar* outp = outAll + (size_t)b*HIDx*NC;

    __shared__ __align__(16) uchar Als[128*64];
    __shared__ __align__(16) uchar Bls[128*64];
    int t = threadIdx.x;
    int lane = t & 63, wave = t >> 6;
    int wr = wave >> 1, wc = wave & 1;
    int q = lane >> 4, c16 = lane & 15;
    int r0 = rt*128, n0 = ct*128;
    int lrow = lane >> 2;
    int pu   = lane & 3;
    f32x4 acc[4][4] = {};

    for (int kk = 0; kk < K; kk += 64) {
        #pragma unroll
        for (int r = 0; r < 2; ++r) {
            int chunk = wave*2 + r;
            int row = chunk*16 + lrow;
            int sl = pu ^ ((row>>1)&3) ^ ((row>>4)&3);
            gload_lds16(Ash + (size_t)(r0+row)*K + kk + sl*16, Als + chunk*1024);
            if (!TRB)
                gload_lds16(B + (size_t)(n0+row)*K + kk + sl*16, Bls + chunk*1024);
        }
        if (TRB) {
            int pi  = t & 31;          // k-pair within 64-k tile
            int nc8 = t >> 5;          // 8 col-groups of 16
            int hk = kk + 2*pi;
            const uchar* g0 = B + (size_t)hk*NC + n0 + nc8*16;
            const uchar* g1 = g0 + NC;
            float4 v0 = *(const float4*)g0;
            float4 v1 = *(const float4*)g1;
            const uchar* pa = (const uchar*)&v0;
            const uchar* qa = (const uchar*)&v1;
            int kb = 2*pi;
            int s  = kb >> 4;
            #pragma unroll
            for (int e = 0; e < 16; ++e) {
                int row = nc8*16 + e;
                int ps = s ^ ((row>>1)&3) ^ ((row>>4)&3);
                *(ushort*)(Bls + row*64 + ps*16 + (kb & 15)) =
                    (ushort)pa[e] | ((ushort)qa[e] << 8);
            }
        }
        __syncthreads();
        #pragma unroll
        for (int ks = 0; ks < 64; ks += 32) {
            fp8x8 af[4], bfr[4];
            #pragma unroll
            for (int i = 0; i < 4; ++i)
                af[i] = *(const fp8x8*)laddr(Als, wr*64 + i*16 + c16, ks + q*8);
            #pragma unroll
            for (int j = 0; j < 4; ++j)
                bfr[j] = *(const fp8x8*)laddr(Bls, wc*64 + j*16 + c16, ks + q*8);
            #pragma unroll
            for (int i = 0; i < 4; ++i)
                #pragma unroll
                for (int j = 0; j < 4; ++j)
                    acc[i][j] = __builtin_amdgcn_mfma_f32_16x16x32_fp8_fp8(af[i], bfr[j], acc[i][j], 0, 0, 0);
        }
        __syncthreads();
    }
    #pragma unroll
    for (int i = 0; i < 4; ++i) {
        int rowb = r0 + wr*64 + i*16 + q*4;
        #pragma unroll
        for (int j = 0; j < 4; ++j) {
            int col = n0 + wc*64 + j*16 + c16;
            #pragma unroll
            for (int r = 0; r < 4; ++r) {
                float v = acc[i][j][r] * oscale;
                v = fminf(fmaxf(v, -448.0f), 448.0f);
                outp[(size_t)(rowb + r)*NC + col] = f2fp8(v);
            }
        }
    }
}

// ---------------------------------------------------------------------------
// F1: single-pass online softmax-over-b stats for fp8 t1,t2. m and 1/d out.
// ---------------------------------------------------------------------------
__global__ __launch_bounds__(512) void kF1q(
    const uchar* __restrict__ t1, const uchar* __restrict__ t2,
    float* __restrict__ m1, float* __restrict__ rd1,
    float* __restrict__ m2, float* __restrict__ rd2)
{
    int s = blockIdx.x;
    int t = threadIdx.x;
    int hq = t & 63;
    int bq = t >> 6;
    const size_t str = (size_t)SIGx*HIDx;
    size_t base = (size_t)(bq*32)*str + (size_t)s*HIDx + hq*4;

    float mv1[4], dv1[4], mv2[4], dv2[4];
    #pragma unroll
    for (int e = 0; e < 4; ++e) { mv1[e]=-3.0e38f; dv1[e]=0.0f; mv2[e]=-3.0e38f; dv2[e]=0.0f; }

    for (int i = 0; i < 32; ++i) {
        uint u1 = *(const uint*)(t1 + base + (size_t)i*str);
        uint u2 = *(const uint*)(t2 + base + (size_t)i*str);
        float v1[4], v2[4];
        v1[0] = __builtin_amdgcn_cvt_f32_fp8(u1, 0);
        v1[1] = __builtin_amdgcn_cvt_f32_fp8(u1, 1);
        v1[2] = __builtin_amdgcn_cvt_f32_fp8(u1, 2);
        v1[3] = __builtin_amdgcn_cvt_f32_fp8(u1, 3);
        v2[0] = __builtin_amdgcn_cvt_f32_fp8(u2, 0);
        v2[1] = __builtin_amdgcn_cvt_f32_fp8(u2, 1);
        v2[2] = __builtin_amdgcn_cvt_f32_fp8(u2, 2);
        v2[3] = __builtin_amdgcn_cvt_f32_fp8(u2, 3);
        #pragma unroll
        for (int e = 0; e < 4; ++e) {
            float mn;
            mn = fmaxf(mv1[e], v1[e]);
            dv1[e] = dv1[e]*__expf(mv1[e]-mn) + __expf(v1[e]-mn); mv1[e] = mn;
            mn = fmaxf(mv2[e], v2[e]);
            dv2[e] = dv2[e]*__expf(mv2[e]-mn) + __expf(v2[e]-mn); mv2[e] = mn;
        }
    }

    __shared__ float pm1[8][256], pd1[8][256], pm2[8][256], pd2[8][256];
    #pragma unroll
    for (int e = 0; e < 4; ++e) {
        pm1[bq][hq*4+e] = mv1[e]; pd1[bq][hq*4+e] = dv1[e];
        pm2[bq][hq*4+e] = mv2[e]; pd2[bq][hq*4+e] = dv2[e];
    }
    __syncthreads();

    if (t < 256) {
        int h = t;
        float m = -3.0e38f, d = 0.0f;
        #pragma unroll
        for (int j = 0; j < 8; ++j) {
            float mm = pm1[j][h], dd = pd1[j][h];
            float mn = fmaxf(m, mm);
            d = d*__expf(m-mn) + dd*__expf(mm-mn);
            m = mn;
        }
        size_t o = (size_t)s*HIDx + h;
        m1[o] = m; rd1[o] = 1.0f/d;
    } else {
        int h = t - 256;
        float m = -3.0e38f, d = 0.0f;
        #pragma unroll
        for (int j = 0; j < 8; ++j) {
            float mm = pm2[j][h], dd = pd2[j][h];
            float mn = fmaxf(m, mm);
            d = d*__expf(m-mn) + dd*__expf(mm-mn);
            m = mn;
        }
        size_t o = (size_t)s*HIDx + h;
        m2[o] = m; rd2[o] = 1.0f/d;
    }
}

// ---------------------------------------------------------------------------
// F2: sig[b,s] = sum_h exp(t1-m1)*rd1 + exp(t2-m2)*rd2 (fp8 t).
// ---------------------------------------------------------------------------
__global__ __launch_bounds__(256) void kF2q(
    const uchar* __restrict__ t1, const uchar* __restrict__ t2,
    const float* __restrict__ m1, const float* __restrict__ rd1,
    const float* __restrict__ m2, const float* __restrict__ rd2,
    float* __restrict__ sig)
{
    int b = blockIdx.y;
    int sq = threadIdx.x >> 6;
    int s = blockIdx.x*4 + sq;
    int hq = threadIdx.x & 63;
    size_t sh = (size_t)s*HIDx + hq*4;
    size_t tb = ((size_t)b*SIGx + s)*HIDx + hq*4;
    uint u1 = *(const uint*)(t1 + tb);
    uint u2 = *(const uint*)(t2 + tb);
    f32x4 a1 = *(const f32x4*)&m1[sh];
    f32x4 r1 = *(const f32x4*)&rd1[sh];
    f32x4 a2 = *(const f32x4*)&m2[sh];
    f32x4 r2 = *(const f32x4*)&rd2[sh];
    float v = 0.0f;
    v += __expf(__builtin_amdgcn_cvt_f32_fp8(u1,0) - a1.x) * r1.x;
    v += __expf(__builtin_amdgcn_cvt_f32_fp8(u1,1) - a1.y) * r1.y;
    v += __expf(__builtin_amdgcn_cvt_f32_fp8(u1,2) - a1.z) * r1.z;
    v += __expf(__builtin_amdgcn_cvt_f32_fp8(u1,3) - a1.w) * r1.w;
    v += __expf(__builtin_amdgcn_cvt_f32_fp8(u2,0) - a2.x) * r2.x;
    v += __expf(__builtin_amdgcn_cvt_f32_fp8(u2,1) - a2.y) * r2.y;
    v += __expf(__builtin_amdgcn_cvt_f32_fp8(u2,2) - a2.z) * r2.z;
    v += __expf(__builtin_amdgcn_cvt_f32_fp8(u2,3) - a2.w) * r2.w;

    __shared__ float red[256];
    red[threadIdx.x] = v;
    __syncthreads();
    for (int st = 32; st > 0; st >>= 1) {
        if (hq < st) red[threadIdx.x] += red[threadIdx.x + st];
        __syncthreads();
    }
    if (hq == 0) sig[(size_t)b*SIGx + s] = red[sq*64];
}

// ---------------------------------------------------------------------------
// G: out[b,:] = softmax(sig[b,:] @ fcf_w.T + fcf_b)
// ---------------------------------------------------------------------------
__global__ __launch_bounds__(256) void kG_out(
    const float* __restrict__ sig, const float* __restrict__ fw,
    const float* __restrict__ fb, float* __restrict__ out)
{
    int b = blockIdx.x;
    int tid = threadIdx.x;
    __shared__ float red[256];
    __shared__ float logits[OUTx];
    float sv = sig[(size_t)b*SIGx + tid];
    for (int o = 0; o < OUTx; ++o) {
        red[tid] = sv * fw[o*SIGx + tid];
        __syncthreads();
        for (int st = 128; st > 0; st >>= 1) {
            if (tid < st) red[tid] += red[tid+st];
            __syncthreads();
        }
        if (tid == 0) logits[o] = red[0] + fb[o];
        __syncthreads();
    }
    if (tid == 0) {
        float mx = logits[0];
        for (int o = 1; o < OUTx; ++o) mx = fmaxf(mx, logits[o]);
        float dd = 0.0f; float e[OUTx];
        for (int o = 0; o < OUTx; ++o) { e[o] = expf(logits[o]-mx); dd += e[o]; }
        float inv = 1.0f/dd;
        for (int o = 0; o < OUTx; ++o) out[(size_t)b*OUTx + o] = e[o]*inv;
    }
}

// ---------------------------------------------------------------------------
static inline size_t alignup(size_t b) { return (b + 255) & ~(size_t)255; }

extern "C" void kernel_launch(void* const* d_in, const int* in_sizes, int n_in,
                              void* d_out, int out_size, void* d_ws, size_t ws_size,
                              hipStream_t stream)
{
    const float* x   = (const float*)d_in[0];
    // d_in[1] = unif -- dead
    const float* z   = (const float*)d_in[2];
    const float* mg  = (const float*)d_in[3];
    const float* w1  = (const float*)d_in[4];
    const float* b1  = (const float*)d_in[5];
    const float* w2  = (const float*)d_in[6];
    const float* b2  = (const float*)d_in[7];
    const float* c1  = (const float*)d_in[8];
    const float* c2  = (const float*)d_in[9];
    const float* fw  = (const float*)d_in[10];
    const float* fbv = (const float*)d_in[11];
    float* out = (float*)d_out;
    float* flp = out + (size_t)Bx*OUTx;
    (void)in_sizes; (void)n_in; (void)out_size;

    char* ws = (char*)d_ws;
    size_t off = 0;
    auto alloc = [&](size_t bytes) -> char* {
        char* p = ws + off; off += alignup(bytes); return p;
    };
    float*  feat = (float*)alloc((size_t)Bx*Nx*3*4);
    uchar*  c1q  = (uchar*)alloc((size_t)SIGx*Nx);
    uchar*  c2q  = (uchar*)alloc((size_t)SIGx*Nx);
    uchar*  w2tq = (uchar*)alloc((size_t)HIDx*HIDx);
    uchar*  t1   = (uchar*)alloc((size_t)Bx*SIGx*HIDx);   // fp8 t
    uchar*  t2   = (uchar*)alloc((size_t)Bx*SIGx*HIDx);
    float*  m1   = (float*)alloc((size_t)SIGx*HIDx*4);
    float*  d1   = (float*)alloc((size_t)SIGx*HIDx*4);
    float*  m2   = (float*)alloc((size_t)SIGx*HIDx*4);
    float*  d2   = (float*)alloc((size_t)SIGx*HIDx*4);
    float*  sig  = (float*)alloc((size_t)Bx*SIGx*4);
    size_t fixed = off;

    int BC = 1;
    for (int c = Bx; c >= 1; c >>= 1) {
        size_t need = fixed + alignup((size_t)c*Nx*Nx)
                            + 2*alignup((size_t)c*HIDx*Nx);
        if (need <= ws_size) { BC = c; break; }
    }
    uchar* Padj = (uchar*)alloc((size_t)BC*Nx*Nx);       // adj fp8
    uchar* P1   = (uchar*)alloc((size_t)BC*HIDx*Nx);     // h2q
    uchar* P2   = (uchar*)alloc((size_t)BC*HIDx*Nx);     // s1q / s2q

    hipLaunchKernelGGL(kA_sample, dim3(Bx), dim3(Nx), 0, stream, x, z, mg, feat, flp);
    hipLaunchKernelGGL(kPrep, dim3(512), dim3(256), 0, stream, c1, c2, w2, c1q, c2q, w2tq);

    const int nch = Bx / BC;
    for (int c = 0; c < nch; ++c) {
        int b0 = c * BC;
        const float* featL = feat + (size_t)b0*Nx*3;
        uchar* t1L = t1 + (size_t)b0*SIGx*HIDx;
        uchar* t2L = t2 + (size_t)b0*SIGx*HIDx;
        // adj (fp8) + rank-3 pass-1 -> s1q
        hipLaunchKernelGGL(kFuse1, dim3(BC), dim3(512), 0, stream,
                           featL, w1, b1, Padj, P2);
        // t1 = (1/16) * c1q @ s1q -> fp8
        hipLaunchKernelGGL((kGstdQ<512,256,false>), dim3(BC, 4), dim3(256), 0, stream,
                           c1q, P2, t1L, 0.0625f);
        // h2q = (1/16) * w2tq @ s1q^T-staged -> fp8
        hipLaunchKernelGGL((kGstdQ<256,512,true>), dim3(BC, 8), dim3(256), 0, stream,
                           w2tq, P2, P1, 0.0625f);
        // s2q = 0.25 * relu(h2q @ adj + b2) -> fp8
        hipLaunchKernelGGL(kGemmAdjQ, dim3(BC, 8), dim3(256), 0, stream, P1, Padj, b2, P2);
        // t2 = 0.25 * c2q @ s2q  (16 * 1/4 undone) -> fp8
        hipLaunchKernelGGL((kGstdQ<512,256,false>), dim3(BC, 4), dim3(256), 0, stream,
                           c2q, P2, t2L, 0.25f);
    }

    hipLaunchKernelGGL(kF1q, dim3(SIGx), dim3(512), 0, stream,
                       t1, t2, m1, d1, m2, d2);
    hipLaunchKernelGGL(kF2q, dim3(SIGx/4, Bx), dim3(256), 0, stream,
                       t1, t2, m1, d1, m2, d2, sig);
    hipLaunchKernelGGL(kG_out, dim3(Bx), dim3(256), 0, stream, sig, fw, fbv, out);
}